// Round 7
// baseline (237.369 us; speedup 1.0000x reference)
//
#include <hip/hip_runtime.h>
#include <math.h>

#define D_MODEL 2048
#define NE      64
#define BM      128              // gemm tile: 128 tokens x 64 experts
#define KS      8                // split-K factor
#define KSEG    (D_MODEL / KS)   // 256 (acc chain length 256 = proven numerics)
#define NKQ     (KSEG / 4)       // 64 k-quads per segment
#define FB_KC   32
#define FB_NCH  (D_MODEL / FB_KC)

// ---------------- split-K GEMM, LDS-free ------------------------------------
// Lane l owns tokens {m0+l, m0+64+l}; wave wv owns experts 16wv..16wv+15.
// A: per-lane global float4 stream, ring-4 prefetch (2 kq ahead) -> only these
//    ride vmcnt, in-order, compiler inserts counted waits. Consecutive kq hit
//    the same 128B L1 line (7/8 hits).
// W: wave-uniform address -> s_load_dwordx4 into SGPRs (proven in round 6,
//    VGPR=44), rides lgkmcnt. No ds_read anywhere -> no out-of-order SMEM
//    mixing, no lgkmcnt(0) over-drain of A.
// No LDS, no barrier -> per-wave stalls decorrelate; TLP hides s_load drains.
__global__ __launch_bounds__(256) void router_gemm4(
    const float* __restrict__ x, const float* __restrict__ W,
    float* __restrict__ part, int ntiles)
{
    const int t    = threadIdx.x;
    const int tile = blockIdx.x;
    const int ks   = blockIdx.y;
    const int m0   = tile * BM;
    const int k0   = ks * KSEG;
    const int l    = t & 63;
    const int wv   = __builtin_amdgcn_readfirstlane(t >> 6);

    const float* a0 = x + (size_t)(m0 + l) * D_MODEL + k0;        // token l
    const float* a1 = x + (size_t)(m0 + 64 + l) * D_MODEL + k0;   // token l+64
    const float* wseg = W + (size_t)(wv * 16) * D_MODEL + k0;     // uniform

    float acc[2][16] = {};
    float4 r0[4], r1[4];               // ring-4: indices (kq%4) static on unroll

    r0[0] = *(const float4*)(a0);      r1[0] = *(const float4*)(a1);
    r0[1] = *(const float4*)(a0 + 4);  r1[1] = *(const float4*)(a1 + 4);

    #pragma unroll 4
    for (int kq = 0; kq < NKQ; ++kq) {
        const int cur = kq & 3;                    // compile-time after unroll
        const int nxt = (kq + 2) & 3;
        if (kq + 2 < NKQ) {                        // prefetch 2 kq ahead
            r0[nxt] = *(const float4*)(a0 + (kq + 2) * 4);
            r1[nxt] = *(const float4*)(a1 + (kq + 2) * 4);
        }
        const float4 A0 = r0[cur], A1 = r1[cur];
        const float* wk = wseg + kq * 4;
        #pragma unroll
        for (int j = 0; j < 16; ++j) {
            float4 wj = *(const float4*)&wk[(size_t)j * D_MODEL];  // s_load
            acc[0][j] = fmaf(A0.x, wj.x, acc[0][j]);
            acc[0][j] = fmaf(A0.y, wj.y, acc[0][j]);
            acc[0][j] = fmaf(A0.z, wj.z, acc[0][j]);
            acc[0][j] = fmaf(A0.w, wj.w, acc[0][j]);
            acc[1][j] = fmaf(A1.x, wj.x, acc[1][j]);
            acc[1][j] = fmaf(A1.y, wj.y, acc[1][j]);
            acc[1][j] = fmaf(A1.z, wj.z, acc[1][j]);
            acc[1][j] = fmaf(A1.w, wj.w, acc[1][j]);
        }
    }

    // partials laid [tile][ks][row][e]: stats reads become L2-local
    float* dst = part + ((size_t)tile * KS + ks) * (BM * NE) + wv * 16;
    #pragma unroll
    for (int h = 0; h < 2; ++h) {
        float* drow = dst + (size_t)(h * 64 + l) * NE;
        #pragma unroll
        for (int g = 0; g < 4; ++g) {
            float4 v;
            v.x = acc[h][g * 4 + 0]; v.y = acc[h][g * 4 + 1];
            v.z = acc[h][g * 4 + 2]; v.w = acc[h][g * 4 + 3];
            *(float4*)&drow[g * 4] = v;
        }
    }
}

// ---------------- reduce 8 partials + fused stats (64 tokens/block) ---------
__global__ __launch_bounds__(256) void router_stats2(
    const float* __restrict__ part, float* __restrict__ out,
    float* __restrict__ ws_prob, float* __restrict__ ws_z,
    int* __restrict__ ws_cnt, int Ntok, int ntiles_g)
{
    __shared__ float sL[64][NE + 1];
    __shared__ float red4[64][4];
    __shared__ int   arg4[64][4];
    __shared__ float smax[64], sinv[64];
    __shared__ float spart[4][NE];
    __shared__ int   hist[NE];

    const int t = threadIdx.x, b = blockIdx.x, m0 = b * 64;
    const int tl = b >> 1, h = b & 1;
    const size_t jstride = (size_t)BM * NE;          // partial-to-partial: 32KB
    const float* base = part + (size_t)tl * KS * jstride + (size_t)h * 64 * NE;

    #pragma unroll
    for (int r = 0; r < 4; ++r) {                    // sum 8 K-partials
        const int q = r * 256 + t;
        const float* p0 = base + (size_t)q * 4;
        float s0 = 0.f, s1 = 0.f, s2 = 0.f, s3 = 0.f;
        #pragma unroll
        for (int j = 0; j < 8; j += 2) {             // fixed order: deterministic
            float4 va = *(const float4*)(p0 + (size_t)j * jstride);
            float4 vb = *(const float4*)(p0 + (size_t)(j + 1) * jstride);
            s0 += va.x + vb.x; s1 += va.y + vb.y;
            s2 += va.z + vb.z; s3 += va.w + vb.w;
        }
        const int row = q >> 4, col = (q & 15) << 2;
        sL[row][col]     = s0; sL[row][col + 1] = s1;
        sL[row][col + 2] = s2; sL[row][col + 3] = s3;
    }
    if (t < NE) hist[t] = 0;
    __syncthreads();

    {   // per-quarter argmax (4 threads per token)
        const int m = t >> 2, qr = t & 3;
        float mx = -3.4e38f; int ag = 0;
        #pragma unroll
        for (int k = 0; k < 16; ++k) {
            const int e = qr * 16 + k;
            float v = sL[m][e];
            if (v > mx) { mx = v; ag = e; }
        }
        red4[m][qr] = mx; arg4[m][qr] = ag;
    }
    __syncthreads();
    if (t < 64) {                                    // combine: first-max kept
        const int m = t;
        float mx = red4[m][0]; int ag = arg4[m][0];
        #pragma unroll
        for (int qr = 1; qr < 4; ++qr)
            if (red4[m][qr] > mx) { mx = red4[m][qr]; ag = arg4[m][qr]; }
        smax[m] = mx;
        out[m0 + m] = (float)ag;                     // expert_index
        atomicAdd(&hist[ag], 1);
    }
    __syncthreads();
    {   // per-quarter expsum
        const int m = t >> 2, qr = t & 3;
        const float mx = smax[m];
        float s = 0.f;
        #pragma unroll
        for (int k = 0; k < 16; ++k) s += expf(sL[m][qr * 16 + k] - mx);
        red4[m][qr] = s;
    }
    __syncthreads();
    if (t < 64) {
        const int m = t;
        float s = ((red4[m][0] + red4[m][1]) + red4[m][2]) + red4[m][3];
        float inv = 1.f / s;
        sinv[m] = inv;
        out[Ntok + m0 + m] = inv;                    // expert_prob
        float lse = smax[m] + logf(s);
        float z = lse * lse;
        #pragma unroll
        for (int off = 32; off > 0; off >>= 1) z += __shfl_down(z, off, 64);
        if (t == 0) ws_z[b] = z;
    }
    __syncthreads();
    {   // probsum: wave mg covers 16 tokens, lane = expert
        const int e = t & 63, mg = t >> 6;
        float pa = 0.f;
        #pragma unroll
        for (int k = 0; k < 16; ++k) {
            const int m = mg * 16 + k;
            pa += expf(sL[m][e] - smax[m]) * sinv[m];
        }
        spart[mg][e] = pa;
    }
    __syncthreads();
    if (t < NE) {
        ws_prob[b * NE + t] = ((spart[0][t] + spart[1][t]) + spart[2][t]) + spart[3][t];
        ws_cnt[b * NE + t]  = hist[t];
    }
}

__global__ __launch_bounds__(64) void router_final_kernel(
    const float* __restrict__ ws_prob, const float* __restrict__ ws_z,
    const int* __restrict__ ws_cnt, float* __restrict__ out,
    int Ntok, int nblocks)
{
    const int e = threadIdx.x;
    float ps = 0.f; int c = 0;
    for (int blk = 0; blk < nblocks; ++blk) {        // fixed order: deterministic
        ps += ws_prob[blk * NE + e];
        c  += ws_cnt[blk * NE + e];
    }
    float z = 0.f;
    for (int blk = e; blk < nblocks; blk += 64) z += ws_z[blk];
    #pragma unroll
    for (int off = 32; off > 0; off >>= 1) z += __shfl_down(z, off, 64);

    float fN = (float)Ntok;
    float fp = ((float)c / fN) * (ps / fN);
    #pragma unroll
    for (int off = 32; off > 0; off >>= 1) fp += __shfl_down(fp, off, 64);

    out[2 * Ntok + e] = (float)c;
    if (e == 0) {
        int cap = (Ntok + NE - 1) / NE;
        if (cap < 4) cap = 4;
        float aux = 0.01f * (float)NE * fp + 1e-3f * (z / fN);
        out[2 * Ntok + NE]     = (float)cap;
        out[2 * Ntok + NE + 1] = aux;
    }
}

// ---------------- fallback (round-1 proven fused path) ----------------------
__global__ __launch_bounds__(256) void router_main_fb(
    const float* __restrict__ x, const float* __restrict__ W,
    float* __restrict__ out, float* __restrict__ ws_prob,
    float* __restrict__ ws_z, int* __restrict__ ws_cnt, int Ntok)
{
    __shared__ __align__(16) float sX[FB_KC][68];
    __shared__ __align__(16) float sW[FB_KC][68];
    __shared__ float sL[64][65];
    __shared__ float smax[64], sinv[64];
    __shared__ float spart[4][NE];
    __shared__ int   hist[NE];

    const int t = threadIdx.x, b = blockIdx.x, m0 = b * 64;
    const int mq = t & 15, nq = t >> 4;
    const int r1 = t >> 3, r2 = r1 + 32, c1 = (t & 7) << 2;
    const float* xp1 = x + (size_t)(m0 + r1) * D_MODEL + c1;
    const float* xp2 = x + (size_t)(m0 + r2) * D_MODEL + c1;
    const float* wp1 = W + (size_t)r1 * D_MODEL + c1;
    const float* wp2 = W + (size_t)r2 * D_MODEL + c1;
    float4 ax1 = *(const float4*)xp1, ax2 = *(const float4*)xp2;
    float4 aw1 = *(const float4*)wp1, aw2 = *(const float4*)wp2;
    float a1[4][4] = {}, a2[4][4] = {};
    for (int ch = 0; ch < FB_NCH; ++ch) {
        __syncthreads();
        sX[c1+0][r1] = ax1.x; sX[c1+1][r1] = ax1.y; sX[c1+2][r1] = ax1.z; sX[c1+3][r1] = ax1.w;
        sX[c1+0][r2] = ax2.x; sX[c1+1][r2] = ax2.y; sX[c1+2][r2] = ax2.z; sX[c1+3][r2] = ax2.w;
        sW[c1+0][r1] = aw1.x; sW[c1+1][r1] = aw1.y; sW[c1+2][r1] = aw1.z; sW[c1+3][r1] = aw1.w;
        sW[c1+0][r2] = aw2.x; sW[c1+1][r2] = aw2.y; sW[c1+2][r2] = aw2.z; sW[c1+3][r2] = aw2.w;
        __syncthreads();
        if (ch + 1 < FB_NCH) {
            xp1 += FB_KC; xp2 += FB_KC; wp1 += FB_KC; wp2 += FB_KC;
            ax1 = *(const float4*)xp1; ax2 = *(const float4*)xp2;
            aw1 = *(const float4*)wp1; aw2 = *(const float4*)wp2;
        }
        #pragma unroll
        for (int k = 0; k < FB_KC; ++k) {
            float4 xa = *(const float4*)&sX[k][mq << 2];
            float4 wb = *(const float4*)&sW[k][nq << 2];
            float (*A)[4] = (k < FB_KC / 2) ? a1 : a2;
            A[0][0] = fmaf(xa.x, wb.x, A[0][0]); A[0][1] = fmaf(xa.x, wb.y, A[0][1]);
            A[0][2] = fmaf(xa.x, wb.z, A[0][2]); A[0][3] = fmaf(xa.x, wb.w, A[0][3]);
            A[1][0] = fmaf(xa.y, wb.x, A[1][0]); A[1][1] = fmaf(xa.y, wb.y, A[1][1]);
            A[1][2] = fmaf(xa.y, wb.z, A[1][2]); A[1][3] = fmaf(xa.y, wb.w, A[1][3]);
            A[2][0] = fmaf(xa.z, wb.x, A[2][0]); A[2][1] = fmaf(xa.z, wb.y, A[2][1]);
            A[2][2] = fmaf(xa.z, wb.z, A[2][2]); A[2][3] = fmaf(xa.z, wb.w, A[2][3]);
            A[3][0] = fmaf(xa.w, wb.x, A[3][0]); A[3][1] = fmaf(xa.w, wb.y, A[3][1]);
            A[3][2] = fmaf(xa.w, wb.z, A[3][2]); A[3][3] = fmaf(xa.w, wb.w, A[3][3]);
        }
    }
    #pragma unroll
    for (int i = 0; i < 4; ++i)
        #pragma unroll
        for (int j = 0; j < 4; ++j)
            sL[(mq << 2) + i][(nq << 2) + j] = a1[i][j] + a2[i][j];
    if (t < NE) hist[t] = 0;
    __syncthreads();
    if (t < 64) {
        const int m = t;
        float mx = sL[m][0]; int arg = 0;
        for (int e = 1; e < NE; ++e) { float v = sL[m][e]; if (v > mx) { mx = v; arg = e; } }
        float s = 0.f;
        for (int e = 0; e < NE; ++e) s += expf(sL[m][e] - mx);
        float inv = 1.f / s;
        out[m0 + m] = (float)arg; out[Ntok + m0 + m] = inv;
        smax[m] = mx; sinv[m] = inv;
        atomicAdd(&hist[arg], 1);
        float lse = mx + logf(s); float z = lse * lse;
        for (int off = 32; off > 0; off >>= 1) z += __shfl_down(z, off, 64);
        if (t == 0) ws_z[b] = z;
    }
    __syncthreads();
    {
        const int e = t & 63, mg = t >> 6;
        float pa = 0.f;
        for (int m = mg * 16; m < mg * 16 + 16; ++m) pa += expf(sL[m][e] - smax[m]) * sinv[m];
        spart[mg][e] = pa;
    }
    __syncthreads();
    if (t < NE) {
        ws_prob[b * NE + t] = spart[0][t] + spart[1][t] + spart[2][t] + spart[3][t];
        ws_cnt[b * NE + t]  = hist[t];
    }
}

extern "C" void kernel_launch(void* const* d_in, const int* in_sizes, int n_in,
                              void* d_out, int out_size, void* d_ws, size_t ws_size,
                              hipStream_t stream)
{
    const float* x = (const float*)d_in[0];
    const float* W = (const float*)d_in[1];
    float* out = (float*)d_out;

    const int Ntok = in_sizes[0] / D_MODEL;          // 16384

    const int ntiles_g = Ntok / BM;                  // 128
    const int nstat    = Ntok / 64;                  // 256
    const size_t part_elems = (size_t)KS * ntiles_g * BM * NE;   // 8.39M floats
    const size_t need = (part_elems + (size_t)nstat * NE + nstat) * 4
                      + (size_t)nstat * NE * 4 + 1024;

    if ((Ntok % BM) == 0 && ws_size >= need) {
        float* ws_part = (float*)d_ws;
        float* ws_prob = ws_part + part_elems;
        float* ws_z    = ws_prob + (size_t)nstat * NE;
        int*   ws_cnt  = (int*)(ws_z + nstat);

        dim3 grid(ntiles_g, KS);
        router_gemm4<<<grid, 256, 0, stream>>>(x, W, ws_part, ntiles_g);
        router_stats2<<<nstat, 256, 0, stream>>>(ws_part, out, ws_prob, ws_z, ws_cnt, Ntok, ntiles_g);
        router_final_kernel<<<1, 64, 0, stream>>>(ws_prob, ws_z, ws_cnt, out, Ntok, nstat);
    } else {
        const int nb = Ntok / 64;
        float* ws_prob = (float*)d_ws;
        float* ws_z    = ws_prob + (size_t)nb * NE;
        int*   ws_cnt  = (int*)(ws_z + nb);
        router_main_fb<<<nb, 256, 0, stream>>>(x, W, out, ws_prob, ws_z, ws_cnt, Ntok);
        router_final_kernel<<<1, 64, 0, stream>>>(ws_prob, ws_z, ws_cnt, out, Ntok, nb);
    }
}

// Round 8
// 171.921 us; speedup vs baseline: 1.3807x; 1.3807x over previous
//
#include <hip/hip_runtime.h>
#include <math.h>

#define D_MODEL 2048
#define NE      64
#define TB      64               // tokens per gemm block
#define KS      8                // split-K factor
#define KSEG    (D_MODEL / KS)   // 256 (acc chain length 256 = proven numerics)
#define NKQ     (KSEG / 4)       // 64 k-quads per segment
#define FB_KC   32
#define FB_NCH  (D_MODEL / FB_KC)

// async 16B global->LDS DMA (LDS dest = wave-uniform base + lane*16)
__device__ __forceinline__ void async_copy16(const float* g, float* l) {
    __builtin_amdgcn_global_load_lds(
        (const __attribute__((address_space(1))) unsigned int*)g,
        (__attribute__((address_space(3))) unsigned int*)l, 16, 0, 0);
}

// ---------------- split-K GEMM: 64 tok x 64 exp x KSEG, one-shot LDS --------
// A: WHOLE segment staged once via DMA (64KB, coalesced), ONE vmcnt(0)+barrier
//    per kernel -> no per-chunk convoy (round-6 flaw), no uncoalesced streams
//    (round-7 flaw: 2.7x overfetch).
// W: wave-uniform s_load -> SGPRs (proven round 6), lgkmcnt; drains overlap
//    across 4 waves/SIMD since waves are unsynchronized in the loop.
// LDS swizzle: row m's source-quad q stored at slot (q+m)&63; read of quad kq
//    at slot (kq+l)&63. Both-sides consistent (rule #21).
__global__ __launch_bounds__(512) void router_gemm5(
    const float* __restrict__ x, const float* __restrict__ W,
    float* __restrict__ part, int ntiles)
{
    __shared__ __align__(16) float sA[TB * KSEG];    // 64KB -> 2 blocks/CU

    const int t    = threadIdx.x;
    const int tile = blockIdx.x;
    const int ks   = blockIdx.y;
    const int m0   = tile * TB;
    const int k0   = ks * KSEG;
    const int l    = t & 63;
    const int wv   = __builtin_amdgcn_readfirstlane(t >> 6);   // 0..7

    // one-shot stage: 8 DMA instrs; instr i: wave wv writes row m = 8i+wv,
    // lane l supplies source quad q = (l - m) & 63 (lands at slot l)
    #pragma unroll
    for (int i = 0; i < 8; ++i) {
        const int m = i * 8 + wv;
        const int q = (l - m) & 63;
        async_copy16(x + (size_t)(m0 + m) * D_MODEL + k0 + (q << 2),
                     &sA[i * 2048 + wv * 256]);
    }
    asm volatile("s_waitcnt vmcnt(0)" ::: "memory");
    __builtin_amdgcn_s_barrier();

    const float* wbase = W + (size_t)(wv * 8) * D_MODEL + k0;  // experts wv*8..+7
    const float* arow  = &sA[l << 8];                          // token l's row
    float acc[8] = {};                                         // 8 experts

    #pragma unroll 2
    for (int kq = 0; kq < NKQ; ++kq) {
        float4 a = *(const float4*)&arow[((kq + l) & 63) << 2];
        #pragma unroll
        for (int j = 0; j < 8; ++j) {
            float4 wj = *(const float4*)&wbase[(size_t)j * D_MODEL + kq * 4];
            acc[j] = fmaf(a.x, wj.x, acc[j]);
            acc[j] = fmaf(a.y, wj.y, acc[j]);
            acc[j] = fmaf(a.z, wj.z, acc[j]);
            acc[j] = fmaf(a.w, wj.w, acc[j]);
        }
    }

    // partials [tile][ks][row][e]
    float* dst = part + (((size_t)tile * KS + ks) * TB + l) * NE + wv * 8;
    float4 v0, v1;
    v0.x = acc[0]; v0.y = acc[1]; v0.z = acc[2]; v0.w = acc[3];
    v1.x = acc[4]; v1.y = acc[5]; v1.z = acc[6]; v1.w = acc[7];
    *(float4*)&dst[0] = v0;
    *(float4*)&dst[4] = v1;
}

// ---------------- reduce 8 partials + fused stats, 1024 thr (4 waves/SIMD) --
__global__ __launch_bounds__(1024) void router_stats3(
    const float* __restrict__ part, float* __restrict__ out,
    float* __restrict__ ws_prob, float* __restrict__ ws_z,
    int* __restrict__ ws_cnt, int Ntok)
{
    __shared__ float sL[64][NE + 1];
    __shared__ float red16[64][16];
    __shared__ int   arg16[64][16];
    __shared__ float smax[64], sinv[64];
    __shared__ float spart[16][NE];
    __shared__ int   hist[NE];

    const int t = threadIdx.x, b = blockIdx.x, m0 = b * 64;
    const float* base = part + (size_t)b * KS * (64 * NE);

    {   // sum 8 K-partials: thread t owns float4 #t (fixed order: deterministic)
        const float* p0 = base + (size_t)t * 4;
        float s0 = 0.f, s1 = 0.f, s2 = 0.f, s3 = 0.f;
        #pragma unroll
        for (int j = 0; j < KS; ++j) {
            float4 v = *(const float4*)(p0 + (size_t)j * (64 * NE));
            s0 += v.x; s1 += v.y; s2 += v.z; s3 += v.w;
        }
        const int row = t >> 4, col = (t & 15) << 2;
        sL[row][col]     = s0; sL[row][col + 1] = s1;
        sL[row][col + 2] = s2; sL[row][col + 3] = s3;
    }
    if (t < NE) hist[t] = 0;
    __syncthreads();

    {   // argmax: 16 threads/token, 4 experts each (ascending -> first-max ok)
        const int m = t >> 4, qr = t & 15;
        float mx = -3.4e38f; int ag = qr * 4;
        #pragma unroll
        for (int k = 0; k < 4; ++k) {
            const int e = qr * 4 + k;
            float v = sL[m][e];
            if (v > mx) { mx = v; ag = e; }
        }
        red16[m][qr] = mx; arg16[m][qr] = ag;
    }
    __syncthreads();
    if (t < 64) {                            // combine ascending: first-max kept
        const int m = t;
        float mx = red16[m][0]; int ag = arg16[m][0];
        #pragma unroll
        for (int qr = 1; qr < 16; ++qr)
            if (red16[m][qr] > mx) { mx = red16[m][qr]; ag = arg16[m][qr]; }
        smax[m] = mx;
        out[m0 + m] = (float)ag;             // expert_index
        atomicAdd(&hist[ag], 1);
    }
    __syncthreads();
    {   // expsum: 16 threads/token
        const int m = t >> 4, qr = t & 15;
        const float mx = smax[m];
        float s = 0.f;
        #pragma unroll
        for (int k = 0; k < 4; ++k) s += expf(sL[m][qr * 4 + k] - mx);
        red16[m][qr] = s;
    }
    __syncthreads();
    if (t < 64) {
        const int m = t;
        float s = 0.f;
        #pragma unroll
        for (int qr = 0; qr < 16; ++qr) s += red16[m][qr];   // fixed order
        float inv = 1.f / s;
        sinv[m] = inv;
        out[Ntok + m0 + m] = inv;            // expert_prob
        float lse = smax[m] + logf(s);
        float z = lse * lse;
        #pragma unroll
        for (int off = 32; off > 0; off >>= 1) z += __shfl_down(z, off, 64);
        if (t == 0) ws_z[b] = z;
    }
    __syncthreads();
    {   // probsum: 16 waves, wave g covers 4 tokens, lane = expert
        const int e = t & 63, g = t >> 6;
        float pa = 0.f;
        #pragma unroll
        for (int k = 0; k < 4; ++k) {
            const int m = g * 4 + k;
            pa += expf(sL[m][e] - smax[m]) * sinv[m];
        }
        spart[g][e] = pa;
    }
    __syncthreads();
    if (t < NE) {
        float ps = 0.f;
        #pragma unroll
        for (int g = 0; g < 16; ++g) ps += spart[g][t];      // fixed order
        ws_prob[b * NE + t] = ps;
        ws_cnt[b * NE + t]  = hist[t];
    }
}

__global__ __launch_bounds__(64) void router_final_kernel(
    const float* __restrict__ ws_prob, const float* __restrict__ ws_z,
    const int* __restrict__ ws_cnt, float* __restrict__ out,
    int Ntok, int nblocks)
{
    const int e = threadIdx.x;
    float ps = 0.f; int c = 0;
    for (int blk = 0; blk < nblocks; ++blk) {    // fixed order: deterministic
        ps += ws_prob[blk * NE + e];
        c  += ws_cnt[blk * NE + e];
    }
    float z = 0.f;
    for (int blk = e; blk < nblocks; blk += 64) z += ws_z[blk];
    #pragma unroll
    for (int off = 32; off > 0; off >>= 1) z += __shfl_down(z, off, 64);

    float fN = (float)Ntok;
    float fp = ((float)c / fN) * (ps / fN);
    #pragma unroll
    for (int off = 32; off > 0; off >>= 1) fp += __shfl_down(fp, off, 64);

    out[2 * Ntok + e] = (float)c;
    if (e == 0) {
        int cap = (Ntok + NE - 1) / NE;
        if (cap < 4) cap = 4;
        float aux = 0.01f * (float)NE * fp + 1e-3f * (z / fN);
        out[2 * Ntok + NE]     = (float)cap;
        out[2 * Ntok + NE + 1] = aux;
    }
}

// ---------------- fallback (round-1 proven fused path) ----------------------
__global__ __launch_bounds__(256) void router_main_fb(
    const float* __restrict__ x, const float* __restrict__ W,
    float* __restrict__ out, float* __restrict__ ws_prob,
    float* __restrict__ ws_z, int* __restrict__ ws_cnt, int Ntok)
{
    __shared__ __align__(16) float sX[FB_KC][68];
    __shared__ __align__(16) float sW[FB_KC][68];
    __shared__ float sL[64][65];
    __shared__ float smax[64], sinv[64];
    __shared__ float spart[4][NE];
    __shared__ int   hist[NE];

    const int t = threadIdx.x, b = blockIdx.x, m0 = b * 64;
    const int mq = t & 15, nq = t >> 4;
    const int r1 = t >> 3, r2 = r1 + 32, c1 = (t & 7) << 2;
    const float* xp1 = x + (size_t)(m0 + r1) * D_MODEL + c1;
    const float* xp2 = x + (size_t)(m0 + r2) * D_MODEL + c1;
    const float* wp1 = W + (size_t)r1 * D_MODEL + c1;
    const float* wp2 = W + (size_t)r2 * D_MODEL + c1;
    float4 ax1 = *(const float4*)xp1, ax2 = *(const float4*)xp2;
    float4 aw1 = *(const float4*)wp1, aw2 = *(const float4*)wp2;
    float a1[4][4] = {}, a2[4][4] = {};
    for (int ch = 0; ch < FB_NCH; ++ch) {
        __syncthreads();
        sX[c1+0][r1] = ax1.x; sX[c1+1][r1] = ax1.y; sX[c1+2][r1] = ax1.z; sX[c1+3][r1] = ax1.w;
        sX[c1+0][r2] = ax2.x; sX[c1+1][r2] = ax2.y; sX[c1+2][r2] = ax2.z; sX[c1+3][r2] = ax2.w;
        sW[c1+0][r1] = aw1.x; sW[c1+1][r1] = aw1.y; sW[c1+2][r1] = aw1.z; sW[c1+3][r1] = aw1.w;
        sW[c1+0][r2] = aw2.x; sW[c1+1][r2] = aw2.y; sW[c1+2][r2] = aw2.z; sW[c1+3][r2] = aw2.w;
        __syncthreads();
        if (ch + 1 < FB_NCH) {
            xp1 += FB_KC; xp2 += FB_KC; wp1 += FB_KC; wp2 += FB_KC;
            ax1 = *(const float4*)xp1; ax2 = *(const float4*)xp2;
            aw1 = *(const float4*)wp1; aw2 = *(const float4*)wp2;
        }
        #pragma unroll
        for (int k = 0; k < FB_KC; ++k) {
            float4 xa = *(const float4*)&sX[k][mq << 2];
            float4 wb = *(const float4*)&sW[k][nq << 2];
            float (*A)[4] = (k < FB_KC / 2) ? a1 : a2;
            A[0][0] = fmaf(xa.x, wb.x, A[0][0]); A[0][1] = fmaf(xa.x, wb.y, A[0][1]);
            A[0][2] = fmaf(xa.x, wb.z, A[0][2]); A[0][3] = fmaf(xa.x, wb.w, A[0][3]);
            A[1][0] = fmaf(xa.y, wb.x, A[1][0]); A[1][1] = fmaf(xa.y, wb.y, A[1][1]);
            A[1][2] = fmaf(xa.y, wb.z, A[1][2]); A[1][3] = fmaf(xa.y, wb.w, A[1][3]);
            A[2][0] = fmaf(xa.z, wb.x, A[2][0]); A[2][1] = fmaf(xa.z, wb.y, A[2][1]);
            A[2][2] = fmaf(xa.z, wb.z, A[2][2]); A[2][3] = fmaf(xa.z, wb.w, A[2][3]);
            A[3][0] = fmaf(xa.w, wb.x, A[3][0]); A[3][1] = fmaf(xa.w, wb.y, A[3][1]);
            A[3][2] = fmaf(xa.w, wb.z, A[3][2]); A[3][3] = fmaf(xa.w, wb.w, A[3][3]);
        }
    }
    #pragma unroll
    for (int i = 0; i < 4; ++i)
        #pragma unroll
        for (int j = 0; j < 4; ++j)
            sL[(mq << 2) + i][(nq << 2) + j] = a1[i][j] + a2[i][j];
    if (t < NE) hist[t] = 0;
    __syncthreads();
    if (t < 64) {
        const int m = t;
        float mx = sL[m][0]; int arg = 0;
        for (int e = 1; e < NE; ++e) { float v = sL[m][e]; if (v > mx) { mx = v; arg = e; } }
        float s = 0.f;
        for (int e = 0; e < NE; ++e) s += expf(sL[m][e] - mx);
        float inv = 1.f / s;
        out[m0 + m] = (float)arg; out[Ntok + m0 + m] = inv;
        smax[m] = mx; sinv[m] = inv;
        atomicAdd(&hist[arg], 1);
        float lse = mx + logf(s); float z = lse * lse;
        for (int off = 32; off > 0; off >>= 1) z += __shfl_down(z, off, 64);
        if (t == 0) ws_z[b] = z;
    }
    __syncthreads();
    {
        const int e = t & 63, mg = t >> 6;
        float pa = 0.f;
        for (int m = mg * 16; m < mg * 16 + 16; ++m) pa += expf(sL[m][e] - smax[m]) * sinv[m];
        spart[mg][e] = pa;
    }
    __syncthreads();
    if (t < NE) {
        ws_prob[b * NE + t] = spart[0][t] + spart[1][t] + spart[2][t] + spart[3][t];
        ws_cnt[b * NE + t]  = hist[t];
    }
}

extern "C" void kernel_launch(void* const* d_in, const int* in_sizes, int n_in,
                              void* d_out, int out_size, void* d_ws, size_t ws_size,
                              hipStream_t stream)
{
    const float* x = (const float*)d_in[0];
    const float* W = (const float*)d_in[1];
    float* out = (float*)d_out;

    const int Ntok = in_sizes[0] / D_MODEL;          // 16384
    const int ntiles = Ntok / TB;                    // 256

    const size_t part_elems = (size_t)ntiles * KS * TB * NE;     // 8.39M floats
    const size_t need = (part_elems + (size_t)ntiles * NE + ntiles) * 4
                      + (size_t)ntiles * NE * 4 + 1024;

    if ((Ntok % TB) == 0 && ws_size >= need) {
        float* ws_part = (float*)d_ws;
        float* ws_prob = ws_part + part_elems;
        float* ws_z    = ws_prob + (size_t)ntiles * NE;
        int*   ws_cnt  = (int*)(ws_z + ntiles);

        dim3 grid(ntiles, KS);
        router_gemm5<<<grid, 512, 0, stream>>>(x, W, ws_part, ntiles);
        router_stats3<<<ntiles, 1024, 0, stream>>>(ws_part, out, ws_prob, ws_z, ws_cnt, Ntok);
        router_final_kernel<<<1, 64, 0, stream>>>(ws_prob, ws_z, ws_cnt, out, Ntok, ntiles);
    } else {
        const int nb = Ntok / 64;
        float* ws_prob = (float*)d_ws;
        float* ws_z    = ws_prob + (size_t)nb * NE;
        int*   ws_cnt  = (int*)(ws_z + nb);
        router_main_fb<<<nb, 256, 0, stream>>>(x, W, out, ws_prob, ws_z, ws_cnt, Ntok);
        router_final_kernel<<<1, 64, 0, stream>>>(ws_prob, ws_z, ws_cnt, out, Ntok, nb);
    }
}

// Round 9
// 155.036 us; speedup vs baseline: 1.5311x; 1.1089x over previous
//
#include <hip/hip_runtime.h>
#include <math.h>

#define D_MODEL 2048
#define NE      64
#define TB      256              // tokens per gemm block
#define KS      8                // split-K factor
#define KSEG    (D_MODEL / KS)   // 256 (acc chain length 256 = proven numerics)
#define KC      32               // k-chunk (floats); 8 chunks per segment
#define NCH     (KSEG / KC)      // 8
#define FB_KC   32
#define FB_NCH  (D_MODEL / FB_KC)

// async 16B global->LDS DMA (LDS dest = wave-uniform base + lane*16)
__device__ __forceinline__ void async_copy16(const float* g, float* l) {
    __builtin_amdgcn_global_load_lds(
        (const __attribute__((address_space(1))) unsigned int*)g,
        (__attribute__((address_space(3))) unsigned int*)l, 16, 0, 0);
}

// ---------------- split-K GEMM: 256 tok x 64 exp x KSEG ---------------------
// Key ratio: lane owns 4 tokens, wave owns 8 experts -> per kq: 128 FMAs
// (256 SIMD-cyc) per 8 scalar W-loads = 32 cyc/s_load (r6=16, r8=8: the
// round-8 regression isolated this as the binding constraint).
// A: chunked DMA (2 x 32KB dbuf), counted vmcnt(4) keeps next chunk in
//    flight; only DMAs ride vmcnt (W = s_load/lgkm) -> count is exact.
// LDS swizzle: row m stores quad q at slot (q+m)&7; read quad kq at slot
//    (kq+m)&7 -> 2-way within 16-lane group (free). Source pre-swizzled.
__global__ __launch_bounds__(512, 4) void router_gemm6(
    const float* __restrict__ x, const float* __restrict__ W,
    float* __restrict__ part, int ntiles)
{
    __shared__ __align__(16) float sA[2][TB * KC];   // 2 x 32KB

    const int t    = threadIdx.x;
    const int tile = blockIdx.x;
    const int ks   = blockIdx.y;
    const int m0   = tile * TB;
    const int k0   = ks * KSEG;
    const int l    = t & 63;
    const int wv   = __builtin_amdgcn_readfirstlane(t >> 6);   // 0..7

    // DMA i (0..3): wave wv stages rows wv*32+i*8 .. +7 of the chunk;
    // lane l -> row +(l>>3), slot l&7, source quad ((l&7)-(l>>3))&7
    const int srow = wv * 32;
    const float* sbase = x + (size_t)(m0 + srow) * D_MODEL + k0
                           + ((((l & 7) - (l >> 3)) & 7) << 2);
    // per-instr source row offset = (l>>3) rows
    const float* ssrc = sbase + (size_t)(l >> 3) * D_MODEL;

    const float* wbase = W + (size_t)(wv * 8) * D_MODEL + k0;  // 8 experts/wave
    float acc[4][8] = {};                                      // 4 tok x 8 exp

    // prologue: stage chunk 0
    #pragma unroll
    for (int i = 0; i < 4; ++i)
        async_copy16(ssrc + (size_t)(i * 8) * D_MODEL,
                     &sA[0][(srow + i * 8) * KC]);

    for (int ch = 0; ch < NCH; ++ch) {
        const int cur = ch & 1;
        if (ch + 1 < NCH) {               // stage next chunk into other buffer
            const float* sn = ssrc + (ch + 1) * KC;
            #pragma unroll
            for (int i = 0; i < 4; ++i)
                async_copy16(sn + (size_t)(i * 8) * D_MODEL,
                             &sA[cur ^ 1][(srow + i * 8) * KC]);
            asm volatile("s_waitcnt vmcnt(4)" ::: "memory");   // ch's 4 done
        } else {
            asm volatile("s_waitcnt vmcnt(0)" ::: "memory");
        }
        __builtin_amdgcn_s_barrier();     // all waves' DMAs for ch visible

        const float* lb = &sA[cur][0];
        const float* wc = wbase + ch * KC;
        #pragma unroll
        for (int kq = 0; kq < KC / 4; ++kq) {
            const int slot = ((kq + l) & 7) << 2;
            float4 a0 = *(const float4*)&lb[(0 * 64 + l) * KC + slot];
            float4 a1 = *(const float4*)&lb[(1 * 64 + l) * KC + slot];
            float4 a2 = *(const float4*)&lb[(2 * 64 + l) * KC + slot];
            float4 a3 = *(const float4*)&lb[(3 * 64 + l) * KC + slot];
            #pragma unroll
            for (int j = 0; j < 8; ++j) {
                float4 wj = *(const float4*)&wc[(size_t)j * D_MODEL + kq * 4];
                acc[0][j] = fmaf(a0.x, wj.x, acc[0][j]);
                acc[0][j] = fmaf(a0.y, wj.y, acc[0][j]);
                acc[0][j] = fmaf(a0.z, wj.z, acc[0][j]);
                acc[0][j] = fmaf(a0.w, wj.w, acc[0][j]);
                acc[1][j] = fmaf(a1.x, wj.x, acc[1][j]);
                acc[1][j] = fmaf(a1.y, wj.y, acc[1][j]);
                acc[1][j] = fmaf(a1.z, wj.z, acc[1][j]);
                acc[1][j] = fmaf(a1.w, wj.w, acc[1][j]);
                acc[2][j] = fmaf(a2.x, wj.x, acc[2][j]);
                acc[2][j] = fmaf(a2.y, wj.y, acc[2][j]);
                acc[2][j] = fmaf(a2.z, wj.z, acc[2][j]);
                acc[2][j] = fmaf(a2.w, wj.w, acc[2][j]);
                acc[3][j] = fmaf(a3.x, wj.x, acc[3][j]);
                acc[3][j] = fmaf(a3.y, wj.y, acc[3][j]);
                acc[3][j] = fmaf(a3.z, wj.z, acc[3][j]);
                acc[3][j] = fmaf(a3.w, wj.w, acc[3][j]);
            }
        }
        __builtin_amdgcn_s_barrier();     // buffer safe to overwrite
    }

    // partials [tile][ks][row 256][e 64]
    float* dst = part + (((size_t)tile * KS + ks) * TB) * NE + wv * 8;
    #pragma unroll
    for (int h = 0; h < 4; ++h) {
        float* drow = dst + (size_t)(h * 64 + l) * NE;
        float4 v0, v1;
        v0.x = acc[h][0]; v0.y = acc[h][1]; v0.z = acc[h][2]; v0.w = acc[h][3];
        v1.x = acc[h][4]; v1.y = acc[h][5]; v1.z = acc[h][6]; v1.w = acc[h][7];
        *(float4*)&drow[0] = v0;
        *(float4*)&drow[4] = v1;
    }
}

// ---------------- reduce 8 partials + fused stats, 1024 thr -----------------
__global__ __launch_bounds__(1024) void router_stats4(
    const float* __restrict__ part, float* __restrict__ out,
    float* __restrict__ ws_prob, float* __restrict__ ws_z,
    int* __restrict__ ws_cnt, int Ntok)
{
    __shared__ float sL[64][NE + 1];
    __shared__ float red16[64][16];
    __shared__ int   arg16[64][16];
    __shared__ float smax[64], sinv[64];
    __shared__ float spart[16][NE];
    __shared__ int   hist[NE];

    const int t = threadIdx.x, b = blockIdx.x, m0 = b * 64;
    // tile = b>>2 (256-token gemm tiles), row group = (b&3)*64
    const float* base = part + (size_t)(b >> 2) * KS * (TB * NE)
                             + (size_t)(b & 3) * (64 * NE);

    {   // sum 8 K-partials: thread t owns float4 #t (fixed order: deterministic)
        const float* p0 = base + (size_t)t * 4;
        float s0 = 0.f, s1 = 0.f, s2 = 0.f, s3 = 0.f;
        #pragma unroll
        for (int j = 0; j < KS; ++j) {
            float4 v = *(const float4*)(p0 + (size_t)j * (TB * NE));
            s0 += v.x; s1 += v.y; s2 += v.z; s3 += v.w;
        }
        const int row = t >> 4, col = (t & 15) << 2;
        sL[row][col]     = s0; sL[row][col + 1] = s1;
        sL[row][col + 2] = s2; sL[row][col + 3] = s3;
    }
    if (t < NE) hist[t] = 0;
    __syncthreads();

    {   // argmax: 16 threads/token, 4 experts each (ascending -> first-max ok)
        const int m = t >> 4, qr = t & 15;
        float mx = -3.4e38f; int ag = qr * 4;
        #pragma unroll
        for (int k = 0; k < 4; ++k) {
            const int e = qr * 4 + k;
            float v = sL[m][e];
            if (v > mx) { mx = v; ag = e; }
        }
        red16[m][qr] = mx; arg16[m][qr] = ag;
    }
    __syncthreads();
    if (t < 64) {                            // combine ascending: first-max kept
        const int m = t;
        float mx = red16[m][0]; int ag = arg16[m][0];
        #pragma unroll
        for (int qr = 1; qr < 16; ++qr)
            if (red16[m][qr] > mx) { mx = red16[m][qr]; ag = arg16[m][qr]; }
        smax[m] = mx;
        out[m0 + m] = (float)ag;             // expert_index
        atomicAdd(&hist[ag], 1);
    }
    __syncthreads();
    {   // expsum: 16 threads/token
        const int m = t >> 4, qr = t & 15;
        const float mx = smax[m];
        float s = 0.f;
        #pragma unroll
        for (int k = 0; k < 4; ++k) s += expf(sL[m][qr * 4 + k] - mx);
        red16[m][qr] = s;
    }
    __syncthreads();
    if (t < 64) {
        const int m = t;
        float s = 0.f;
        #pragma unroll
        for (int qr = 0; qr < 16; ++qr) s += red16[m][qr];   // fixed order
        float inv = 1.f / s;
        sinv[m] = inv;
        out[Ntok + m0 + m] = inv;            // expert_prob
        float lse = smax[m] + logf(s);
        float z = lse * lse;
        #pragma unroll
        for (int off = 32; off > 0; off >>= 1) z += __shfl_down(z, off, 64);
        if (t == 0) ws_z[b] = z;
    }
    __syncthreads();
    {   // probsum: 16 waves, wave g covers 4 tokens, lane = expert
        const int e = t & 63, g = t >> 6;
        float pa = 0.f;
        #pragma unroll
        for (int k = 0; k < 4; ++k) {
            const int m = g * 4 + k;
            pa += expf(sL[m][e] - smax[m]) * sinv[m];
        }
        spart[g][e] = pa;
    }
    __syncthreads();
    if (t < NE) {
        float ps = 0.f;
        #pragma unroll
        for (int g = 0; g < 16; ++g) ps += spart[g][t];      // fixed order
        ws_prob[b * NE + t] = ps;
        ws_cnt[b * NE + t]  = hist[t];
    }
}

__global__ __launch_bounds__(64) void router_final_kernel(
    const float* __restrict__ ws_prob, const float* __restrict__ ws_z,
    const int* __restrict__ ws_cnt, float* __restrict__ out,
    int Ntok, int nblocks)
{
    const int e = threadIdx.x;
    float ps = 0.f; int c = 0;
    for (int blk = 0; blk < nblocks; ++blk) {    // fixed order: deterministic
        ps += ws_prob[blk * NE + e];
        c  += ws_cnt[blk * NE + e];
    }
    float z = 0.f;
    for (int blk = e; blk < nblocks; blk += 64) z += ws_z[blk];
    #pragma unroll
    for (int off = 32; off > 0; off >>= 1) z += __shfl_down(z, off, 64);

    float fN = (float)Ntok;
    float fp = ((float)c / fN) * (ps / fN);
    #pragma unroll
    for (int off = 32; off > 0; off >>= 1) fp += __shfl_down(fp, off, 64);

    out[2 * Ntok + e] = (float)c;
    if (e == 0) {
        int cap = (Ntok + NE - 1) / NE;
        if (cap < 4) cap = 4;
        float aux = 0.01f * (float)NE * fp + 1e-3f * (z / fN);
        out[2 * Ntok + NE]     = (float)cap;
        out[2 * Ntok + NE + 1] = aux;
    }
}

// ---------------- fallback (round-1 proven fused path) ----------------------
__global__ __launch_bounds__(256) void router_main_fb(
    const float* __restrict__ x, const float* __restrict__ W,
    float* __restrict__ out, float* __restrict__ ws_prob,
    float* __restrict__ ws_z, int* __restrict__ ws_cnt, int Ntok)
{
    __shared__ __align__(16) float sX[FB_KC][68];
    __shared__ __align__(16) float sW[FB_KC][68];
    __shared__ float sL[64][65];
    __shared__ float smax[64], sinv[64];
    __shared__ float spart[4][NE];
    __shared__ int   hist[NE];

    const int t = threadIdx.x, b = blockIdx.x, m0 = b * 64;
    const int mq = t & 15, nq = t >> 4;
    const int r1 = t >> 3, r2 = r1 + 32, c1 = (t & 7) << 2;
    const float* xp1 = x + (size_t)(m0 + r1) * D_MODEL + c1;
    const float* xp2 = x + (size_t)(m0 + r2) * D_MODEL + c1;
    const float* wp1 = W + (size_t)r1 * D_MODEL + c1;
    const float* wp2 = W + (size_t)r2 * D_MODEL + c1;
    float4 ax1 = *(const float4*)xp1, ax2 = *(const float4*)xp2;
    float4 aw1 = *(const float4*)wp1, aw2 = *(const float4*)wp2;
    float a1[4][4] = {}, a2[4][4] = {};
    for (int ch = 0; ch < FB_NCH; ++ch) {
        __syncthreads();
        sX[c1+0][r1] = ax1.x; sX[c1+1][r1] = ax1.y; sX[c1+2][r1] = ax1.z; sX[c1+3][r1] = ax1.w;
        sX[c1+0][r2] = ax2.x; sX[c1+1][r2] = ax2.y; sX[c1+2][r2] = ax2.z; sX[c1+3][r2] = ax2.w;
        sW[c1+0][r1] = aw1.x; sW[c1+1][r1] = aw1.y; sW[c1+2][r1] = aw1.z; sW[c1+3][r1] = aw1.w;
        sW[c1+0][r2] = aw2.x; sW[c1+1][r2] = aw2.y; sW[c1+2][r2] = aw2.z; sW[c1+3][r2] = aw2.w;
        __syncthreads();
        if (ch + 1 < FB_NCH) {
            xp1 += FB_KC; xp2 += FB_KC; wp1 += FB_KC; wp2 += FB_KC;
            ax1 = *(const float4*)xp1; ax2 = *(const float4*)xp2;
            aw1 = *(const float4*)wp1; aw2 = *(const float4*)wp2;
        }
        #pragma unroll
        for (int k = 0; k < FB_KC; ++k) {
            float4 xa = *(const float4*)&sX[k][mq << 2];
            float4 wb = *(const float4*)&sW[k][nq << 2];
            float (*A)[4] = (k < FB_KC / 2) ? a1 : a2;
            A[0][0] = fmaf(xa.x, wb.x, A[0][0]); A[0][1] = fmaf(xa.x, wb.y, A[0][1]);
            A[0][2] = fmaf(xa.x, wb.z, A[0][2]); A[0][3] = fmaf(xa.x, wb.w, A[0][3]);
            A[1][0] = fmaf(xa.y, wb.x, A[1][0]); A[1][1] = fmaf(xa.y, wb.y, A[1][1]);
            A[1][2] = fmaf(xa.y, wb.z, A[1][2]); A[1][3] = fmaf(xa.y, wb.w, A[1][3]);
            A[2][0] = fmaf(xa.z, wb.x, A[2][0]); A[2][1] = fmaf(xa.z, wb.y, A[2][1]);
            A[2][2] = fmaf(xa.z, wb.z, A[2][2]); A[2][3] = fmaf(xa.z, wb.w, A[2][3]);
            A[3][0] = fmaf(xa.w, wb.x, A[3][0]); A[3][1] = fmaf(xa.w, wb.y, A[3][1]);
            A[3][2] = fmaf(xa.w, wb.z, A[3][2]); A[3][3] = fmaf(xa.w, wb.w, A[3][3]);
        }
    }
    #pragma unroll
    for (int i = 0; i < 4; ++i)
        #pragma unroll
        for (int j = 0; j < 4; ++j)
            sL[(mq << 2) + i][(nq << 2) + j] = a1[i][j] + a2[i][j];
    if (t < NE) hist[t] = 0;
    __syncthreads();
    if (t < 64) {
        const int m = t;
        float mx = sL[m][0]; int arg = 0;
        for (int e = 1; e < NE; ++e) { float v = sL[m][e]; if (v > mx) { mx = v; arg = e; } }
        float s = 0.f;
        for (int e = 0; e < NE; ++e) s += expf(sL[m][e] - mx);
        float inv = 1.f / s;
        out[m0 + m] = (float)arg; out[Ntok + m0 + m] = inv;
        smax[m] = mx; sinv[m] = inv;
        atomicAdd(&hist[arg], 1);
        float lse = mx + logf(s); float z = lse * lse;
        for (int off = 32; off > 0; off >>= 1) z += __shfl_down(z, off, 64);
        if (t == 0) ws_z[b] = z;
    }
    __syncthreads();
    {
        const int e = t & 63, mg = t >> 6;
        float pa = 0.f;
        for (int m = mg * 16; m < mg * 16 + 16; ++m) pa += expf(sL[m][e] - smax[m]) * sinv[m];
        spart[mg][e] = pa;
    }
    __syncthreads();
    if (t < NE) {
        ws_prob[b * NE + t] = spart[0][t] + spart[1][t] + spart[2][t] + spart[3][t];
        ws_cnt[b * NE + t]  = hist[t];
    }
}

extern "C" void kernel_launch(void* const* d_in, const int* in_sizes, int n_in,
                              void* d_out, int out_size, void* d_ws, size_t ws_size,
                              hipStream_t stream)
{
    const float* x = (const float*)d_in[0];
    const float* W = (const float*)d_in[1];
    float* out = (float*)d_out;

    const int Ntok = in_sizes[0] / D_MODEL;          // 16384
    const int ntiles = Ntok / TB;                    // 64
    const int nstat  = Ntok / 64;                    // 256

    const size_t part_elems = (size_t)ntiles * KS * TB * NE;     // 8.39M floats
    const size_t need = (part_elems + (size_t)nstat * NE + nstat) * 4
                      + (size_t)nstat * NE * 4 + 1024;

    if ((Ntok % TB) == 0 && ws_size >= need) {
        float* ws_part = (float*)d_ws;
        float* ws_prob = ws_part + part_elems;
        float* ws_z    = ws_prob + (size_t)nstat * NE;
        int*   ws_cnt  = (int*)(ws_z + nstat);

        dim3 grid(ntiles, KS);
        router_gemm6<<<grid, 512, 0, stream>>>(x, W, ws_part, ntiles);
        router_stats4<<<nstat, 1024, 0, stream>>>(ws_part, out, ws_prob, ws_z, ws_cnt, Ntok);
        router_final_kernel<<<1, 64, 0, stream>>>(ws_prob, ws_z, ws_cnt, out, Ntok, nstat);
    } else {
        const int nb = Ntok / 64;
        float* ws_prob = (float*)d_ws;
        float* ws_z    = ws_prob + (size_t)nb * NE;
        int*   ws_cnt  = (int*)(ws_z + nb);
        router_main_fb<<<nb, 256, 0, stream>>>(x, W, out, ws_prob, ws_z, ws_cnt, Ntok);
        router_final_kernel<<<1, 64, 0, stream>>>(ws_prob, ws_z, ws_cnt, out, Ntok, nb);
    }
}

// Round 10
// 126.977 us; speedup vs baseline: 1.8694x; 1.2210x over previous
//
#include <hip/hip_runtime.h>
#include <math.h>

#define D_MODEL 2048
#define NE      64
#define TB      256              // tokens per gemm block
#define KS      8                // split-K factor
#define KSEG    (D_MODEL / KS)   // 256 (acc chain length 256 = proven numerics)
#define KC      32               // k-chunk (floats); 8 chunks per segment
#define NCH     (KSEG / KC)      // 8
#define FB_KC   32
#define FB_NCH  (D_MODEL / FB_KC)

// async 16B global->LDS DMA (LDS dest = wave-uniform base + lane*16)
__device__ __forceinline__ void async_copy16(const float* g, float* l) {
    __builtin_amdgcn_global_load_lds(
        (const __attribute__((address_space(1))) unsigned int*)g,
        (__attribute__((address_space(3))) unsigned int*)l, 16, 0, 0);
}

// ---------------- split-K GEMM: 256 tok x 64 exp x KSEG ---------------------
// r9 flaw fixed: W moved from s_load(SMEM, out-of-order lgkm) to LDS
// broadcast ds_read (uniform addr). ALL in-loop loads are now DS ops ->
// in-order -> compiler emits counted lgkmcnt(N) instead of lgkmcnt(0)
// drains per kq (m97-verified behavior). vmcnt carries only the 5 staging
// DMAs/chunk/wave -> counted vmcnt(5) keeps next chunk in flight.
// A LDS layout unchanged from r9 (slot rotation, verified absmax 0.0).
__global__ __launch_bounds__(512, 4) void router_gemm7(
    const float* __restrict__ x, const float* __restrict__ W,
    float* __restrict__ part, int ntiles)
{
    __shared__ __align__(16) float sA[2][TB * KC];   // 2 x 32KB
    __shared__ __align__(16) float sW[2][NE * KC];   // 2 x 8KB

    const int t    = threadIdx.x;
    const int tile = blockIdx.x;
    const int ks   = blockIdx.y;
    const int m0   = tile * TB;
    const int k0   = ks * KSEG;
    const int l    = t & 63;
    const int wv   = __builtin_amdgcn_readfirstlane(t >> 6);   // 0..7

    // A staging (as r9): wave wv stages rows wv*32 .. +31; lane l -> row
    // +(l>>3), slot l&7, source quad ((l&7)-(l>>3))&7 (read undoes rotation)
    const int srow = wv * 32;
    const float* ssrc = x + (size_t)(m0 + srow + (l >> 3)) * D_MODEL + k0
                          + ((((l & 7) - (l >> 3)) & 7) << 2);
    // W staging: lane l -> expert wv*8+(l>>3), quad l&7 (linear dest = linear src)
    const float* wsrc = W + (size_t)(wv * 8 + (l >> 3)) * D_MODEL + k0
                          + ((l & 7) << 2);

    float acc[4][8] = {};                            // 4 tok x 8 exp

    // prologue: stage chunk 0 (5 DMA instrs per wave)
    #pragma unroll
    for (int i = 0; i < 4; ++i)
        async_copy16(ssrc + (size_t)(i * 8) * D_MODEL,
                     &sA[0][(srow + i * 8) * KC]);
    async_copy16(wsrc, &sW[0][wv * 256]);

    for (int ch = 0; ch < NCH; ++ch) {
        const int cur = ch & 1;
        if (ch + 1 < NCH) {               // stage next chunk into other buffer
            const float* sn = ssrc + (ch + 1) * KC;
            #pragma unroll
            for (int i = 0; i < 4; ++i)
                async_copy16(sn + (size_t)(i * 8) * D_MODEL,
                             &sA[cur ^ 1][(srow + i * 8) * KC]);
            async_copy16(wsrc + (ch + 1) * KC, &sW[cur ^ 1][wv * 256]);
            asm volatile("s_waitcnt vmcnt(5)" ::: "memory");   // ch's 5 done
        } else {
            asm volatile("s_waitcnt vmcnt(0)" ::: "memory");
        }
        __builtin_amdgcn_s_barrier();     // all waves' DMAs for ch visible

        const float* lb = &sA[cur][0];
        const float* wb = &sW[cur][wv * 256];        // wave-uniform base
        #pragma unroll
        for (int kq = 0; kq < KC / 4; ++kq) {
            const int slot = ((kq + l) & 7) << 2;
            float4 a0 = *(const float4*)&lb[(0 * 64 + l) * KC + slot];
            float4 a1 = *(const float4*)&lb[(1 * 64 + l) * KC + slot];
            float4 a2 = *(const float4*)&lb[(2 * 64 + l) * KC + slot];
            float4 a3 = *(const float4*)&lb[(3 * 64 + l) * KC + slot];
            #pragma unroll
            for (int j = 0; j < 8; ++j) {
                // uniform address -> broadcast ds_read_b128 (no conflict)
                float4 wj = *(const float4*)&wb[j * KC + kq * 4];
                acc[0][j] = fmaf(a0.x, wj.x, acc[0][j]);
                acc[0][j] = fmaf(a0.y, wj.y, acc[0][j]);
                acc[0][j] = fmaf(a0.z, wj.z, acc[0][j]);
                acc[0][j] = fmaf(a0.w, wj.w, acc[0][j]);
                acc[1][j] = fmaf(a1.x, wj.x, acc[1][j]);
                acc[1][j] = fmaf(a1.y, wj.y, acc[1][j]);
                acc[1][j] = fmaf(a1.z, wj.z, acc[1][j]);
                acc[1][j] = fmaf(a1.w, wj.w, acc[1][j]);
                acc[2][j] = fmaf(a2.x, wj.x, acc[2][j]);
                acc[2][j] = fmaf(a2.y, wj.y, acc[2][j]);
                acc[2][j] = fmaf(a2.z, wj.z, acc[2][j]);
                acc[2][j] = fmaf(a2.w, wj.w, acc[2][j]);
                acc[3][j] = fmaf(a3.x, wj.x, acc[3][j]);
                acc[3][j] = fmaf(a3.y, wj.y, acc[3][j]);
                acc[3][j] = fmaf(a3.z, wj.z, acc[3][j]);
                acc[3][j] = fmaf(a3.w, wj.w, acc[3][j]);
            }
        }
        __builtin_amdgcn_s_barrier();     // buffer safe to overwrite
    }

    // partials [tile][ks][row 256][e 64]
    float* dst = part + (((size_t)tile * KS + ks) * TB) * NE + wv * 8;
    #pragma unroll
    for (int h = 0; h < 4; ++h) {
        float* drow = dst + (size_t)(h * 64 + l) * NE;
        float4 v0, v1;
        v0.x = acc[h][0]; v0.y = acc[h][1]; v0.z = acc[h][2]; v0.w = acc[h][3];
        v1.x = acc[h][4]; v1.y = acc[h][5]; v1.z = acc[h][6]; v1.w = acc[h][7];
        *(float4*)&drow[0] = v0;
        *(float4*)&drow[4] = v1;
    }
}

// ---------------- reduce 8 partials + fused stats, 1024 thr -----------------
__global__ __launch_bounds__(1024) void router_stats4(
    const float* __restrict__ part, float* __restrict__ out,
    float* __restrict__ ws_prob, float* __restrict__ ws_z,
    int* __restrict__ ws_cnt, int Ntok)
{
    __shared__ float sL[64][NE + 1];
    __shared__ float red16[64][16];
    __shared__ int   arg16[64][16];
    __shared__ float smax[64], sinv[64];
    __shared__ float spart[16][NE];
    __shared__ int   hist[NE];

    const int t = threadIdx.x, b = blockIdx.x, m0 = b * 64;
    const float* base = part + (size_t)(b >> 2) * KS * (TB * NE)
                             + (size_t)(b & 3) * (64 * NE);

    {   // sum 8 K-partials: thread t owns float4 #t (fixed order: deterministic)
        const float* p0 = base + (size_t)t * 4;
        float s0 = 0.f, s1 = 0.f, s2 = 0.f, s3 = 0.f;
        #pragma unroll
        for (int j = 0; j < KS; ++j) {
            float4 v = *(const float4*)(p0 + (size_t)j * (TB * NE));
            s0 += v.x; s1 += v.y; s2 += v.z; s3 += v.w;
        }
        const int row = t >> 4, col = (t & 15) << 2;
        sL[row][col]     = s0; sL[row][col + 1] = s1;
        sL[row][col + 2] = s2; sL[row][col + 3] = s3;
    }
    if (t < NE) hist[t] = 0;
    __syncthreads();

    {   // argmax: 16 threads/token, 4 experts each (ascending -> first-max ok)
        const int m = t >> 4, qr = t & 15;
        float mx = -3.4e38f; int ag = qr * 4;
        #pragma unroll
        for (int k = 0; k < 4; ++k) {
            const int e = qr * 4 + k;
            float v = sL[m][e];
            if (v > mx) { mx = v; ag = e; }
        }
        red16[m][qr] = mx; arg16[m][qr] = ag;
    }
    __syncthreads();
    if (t < 64) {                            // combine ascending: first-max kept
        const int m = t;
        float mx = red16[m][0]; int ag = arg16[m][0];
        #pragma unroll
        for (int qr = 1; qr < 16; ++qr)
            if (red16[m][qr] > mx) { mx = red16[m][qr]; ag = arg16[m][qr]; }
        smax[m] = mx;
        out[m0 + m] = (float)ag;             // expert_index
        atomicAdd(&hist[ag], 1);
    }
    __syncthreads();
    {   // expsum: 16 threads/token
        const int m = t >> 4, qr = t & 15;
        const float mx = smax[m];
        float s = 0.f;
        #pragma unroll
        for (int k = 0; k < 4; ++k) s += expf(sL[m][qr * 4 + k] - mx);
        red16[m][qr] = s;
    }
    __syncthreads();
    if (t < 64) {
        const int m = t;
        float s = 0.f;
        #pragma unroll
        for (int qr = 0; qr < 16; ++qr) s += red16[m][qr];   // fixed order
        float inv = 1.f / s;
        sinv[m] = inv;
        out[Ntok + m0 + m] = inv;            // expert_prob
        float lse = smax[m] + logf(s);
        float z = lse * lse;
        #pragma unroll
        for (int off = 32; off > 0; off >>= 1) z += __shfl_down(z, off, 64);
        if (t == 0) ws_z[b] = z;
    }
    __syncthreads();
    {   // probsum: 16 waves, wave g covers 4 tokens, lane = expert
        const int e = t & 63, g = t >> 6;
        float pa = 0.f;
        #pragma unroll
        for (int k = 0; k < 4; ++k) {
            const int m = g * 4 + k;
            pa += expf(sL[m][e] - smax[m]) * sinv[m];
        }
        spart[g][e] = pa;
    }
    __syncthreads();
    if (t < NE) {
        float ps = 0.f;
        #pragma unroll
        for (int g = 0; g < 16; ++g) ps += spart[g][t];      // fixed order
        ws_prob[b * NE + t] = ps;
        ws_cnt[b * NE + t]  = hist[t];
    }
}

// ---------------- final: 4-way parallel over blocks (was serial 256) --------
__global__ __launch_bounds__(256) void router_final2(
    const float* __restrict__ ws_prob, const float* __restrict__ ws_z,
    const int* __restrict__ ws_cnt, float* __restrict__ out,
    int Ntok, int nblocks)
{
    __shared__ float sp[4][NE];
    __shared__ int   sc[4][NE];
    __shared__ float sz[4];

    const int e = threadIdx.x & 63, g = threadIdx.x >> 6;
    const int per = nblocks / 4;
    const int hi  = (g == 3) ? nblocks : (g + 1) * per;

    float ps = 0.f; int c = 0;
    for (int blk = g * per; blk < hi; ++blk) {       // fixed partition: determ.
        ps += ws_prob[blk * NE + e];
        c  += ws_cnt[blk * NE + e];
    }
    sp[g][e] = ps; sc[g][e] = c;

    float z = 0.f;
    for (int blk = (int)threadIdx.x; blk < nblocks; blk += 256) z += ws_z[blk];
    #pragma unroll
    for (int off = 32; off > 0; off >>= 1) z += __shfl_down(z, off, 64);
    if (e == 0) sz[g] = z;
    __syncthreads();

    if (threadIdx.x < 64) {
        const int ee = threadIdx.x;
        float pst = ((sp[0][ee] + sp[1][ee]) + sp[2][ee]) + sp[3][ee];
        int   ct  = ((sc[0][ee] + sc[1][ee]) + sc[2][ee]) + sc[3][ee];
        out[2 * Ntok + ee] = (float)ct;              // counts

        float fN = (float)Ntok;
        float fp = ((float)ct / fN) * (pst / fN);
        #pragma unroll
        for (int off = 32; off > 0; off >>= 1) fp += __shfl_down(fp, off, 64);
        if (ee == 0) {
            float zt = ((sz[0] + sz[1]) + sz[2]) + sz[3];
            int cap = (Ntok + NE - 1) / NE;
            if (cap < 4) cap = 4;
            float aux = 0.01f * (float)NE * fp + 1e-3f * (zt / fN);
            out[2 * Ntok + NE]     = (float)cap;     // capacity
            out[2 * Ntok + NE + 1] = aux;            // aux_loss
        }
    }
}

// ---------------- fallback (round-1 proven fused path) ----------------------
__global__ __launch_bounds__(256) void router_main_fb(
    const float* __restrict__ x, const float* __restrict__ W,
    float* __restrict__ out, float* __restrict__ ws_prob,
    float* __restrict__ ws_z, int* __restrict__ ws_cnt, int Ntok)
{
    __shared__ __align__(16) float sX[FB_KC][68];
    __shared__ __align__(16) float sW[FB_KC][68];
    __shared__ float sL[64][65];
    __shared__ float smax[64], sinv[64];
    __shared__ float spart[4][NE];
    __shared__ int   hist[NE];

    const int t = threadIdx.x, b = blockIdx.x, m0 = b * 64;
    const int mq = t & 15, nq = t >> 4;
    const int r1 = t >> 3, r2 = r1 + 32, c1 = (t & 7) << 2;
    const float* xp1 = x + (size_t)(m0 + r1) * D_MODEL + c1;
    const float* xp2 = x + (size_t)(m0 + r2) * D_MODEL + c1;
    const float* wp1 = W + (size_t)r1 * D_MODEL + c1;
    const float* wp2 = W + (size_t)r2 * D_MODEL + c1;
    float4 ax1 = *(const float4*)xp1, ax2 = *(const float4*)xp2;
    float4 aw1 = *(const float4*)wp1, aw2 = *(const float4*)wp2;
    float a1[4][4] = {}, a2[4][4] = {};
    for (int ch = 0; ch < FB_NCH; ++ch) {
        __syncthreads();
        sX[c1+0][r1] = ax1.x; sX[c1+1][r1] = ax1.y; sX[c1+2][r1] = ax1.z; sX[c1+3][r1] = ax1.w;
        sX[c1+0][r2] = ax2.x; sX[c1+1][r2] = ax2.y; sX[c1+2][r2] = ax2.z; sX[c1+3][r2] = ax2.w;
        sW[c1+0][r1] = aw1.x; sW[c1+1][r1] = aw1.y; sW[c1+2][r1] = aw1.z; sW[c1+3][r1] = aw1.w;
        sW[c1+0][r2] = aw2.x; sW[c1+1][r2] = aw2.y; sW[c1+2][r2] = aw2.z; sW[c1+3][r2] = aw2.w;
        __syncthreads();
        if (ch + 1 < FB_NCH) {
            xp1 += FB_KC; xp2 += FB_KC; wp1 += FB_KC; wp2 += FB_KC;
            ax1 = *(const float4*)xp1; ax2 = *(const float4*)xp2;
            aw1 = *(const float4*)wp1; aw2 = *(const float4*)wp2;
        }
        #pragma unroll
        for (int k = 0; k < FB_KC; ++k) {
            float4 xa = *(const float4*)&sX[k][mq << 2];
            float4 wb = *(const float4*)&sW[k][nq << 2];
            float (*A)[4] = (k < FB_KC / 2) ? a1 : a2;
            A[0][0] = fmaf(xa.x, wb.x, A[0][0]); A[0][1] = fmaf(xa.x, wb.y, A[0][1]);
            A[0][2] = fmaf(xa.x, wb.z, A[0][2]); A[0][3] = fmaf(xa.x, wb.w, A[0][3]);
            A[1][0] = fmaf(xa.y, wb.x, A[1][0]); A[1][1] = fmaf(xa.y, wb.y, A[1][1]);
            A[1][2] = fmaf(xa.y, wb.z, A[1][2]); A[1][3] = fmaf(xa.y, wb.w, A[1][3]);
            A[2][0] = fmaf(xa.z, wb.x, A[2][0]); A[2][1] = fmaf(xa.z, wb.y, A[2][1]);
            A[2][2] = fmaf(xa.z, wb.z, A[2][2]); A[2][3] = fmaf(xa.z, wb.w, A[2][3]);
            A[3][0] = fmaf(xa.w, wb.x, A[3][0]); A[3][1] = fmaf(xa.w, wb.y, A[3][1]);
            A[3][2] = fmaf(xa.w, wb.z, A[3][2]); A[3][3] = fmaf(xa.w, wb.w, A[3][3]);
        }
    }
    #pragma unroll
    for (int i = 0; i < 4; ++i)
        #pragma unroll
        for (int j = 0; j < 4; ++j)
            sL[(mq << 2) + i][(nq << 2) + j] = a1[i][j] + a2[i][j];
    if (t < NE) hist[t] = 0;
    __syncthreads();
    if (t < 64) {
        const int m = t;
        float mx = sL[m][0]; int arg = 0;
        for (int e = 1; e < NE; ++e) { float v = sL[m][e]; if (v > mx) { mx = v; arg = e; } }
        float s = 0.f;
        for (int e = 0; e < NE; ++e) s += expf(sL[m][e] - mx);
        float inv = 1.f / s;
        out[m0 + m] = (float)arg; out[Ntok + m0 + m] = inv;
        smax[m] = mx; sinv[m] = inv;
        atomicAdd(&hist[arg], 1);
        float lse = mx + logf(s); float z = lse * lse;
        for (int off = 32; off > 0; off >>= 1) z += __shfl_down(z, off, 64);
        if (t == 0) ws_z[b] = z;
    }
    __syncthreads();
    {
        const int e = t & 63, mg = t >> 6;
        float pa = 0.f;
        for (int m = mg * 16; m < mg * 16 + 16; ++m) pa += expf(sL[m][e] - smax[m]) * sinv[m];
        spart[mg][e] = pa;
    }
    __syncthreads();
    if (t < NE) {
        ws_prob[b * NE + t] = spart[0][t] + spart[1][t] + spart[2][t] + spart[3][t];
        ws_cnt[b * NE + t]  = hist[t];
    }
}

extern "C" void kernel_launch(void* const* d_in, const int* in_sizes, int n_in,
                              void* d_out, int out_size, void* d_ws, size_t ws_size,
                              hipStream_t stream)
{
    const float* x = (const float*)d_in[0];
    const float* W = (const float*)d_in[1];
    float* out = (float*)d_out;

    const int Ntok = in_sizes[0] / D_MODEL;          // 16384
    const int ntiles = Ntok / TB;                    // 64
    const int nstat  = Ntok / 64;                    // 256

    const size_t part_elems = (size_t)ntiles * KS * TB * NE;     // 8.39M floats
    const size_t need = (part_elems + (size_t)nstat * NE + nstat) * 4
                      + (size_t)nstat * NE * 4 + 1024;

    if ((Ntok % TB) == 0 && (nstat % 4) == 0 && ws_size >= need) {
        float* ws_part = (float*)d_ws;
        float* ws_prob = ws_part + part_elems;
        float* ws_z    = ws_prob + (size_t)nstat * NE;
        int*   ws_cnt  = (int*)(ws_z + nstat);

        dim3 grid(ntiles, KS);
        router_gemm7<<<grid, 512, 0, stream>>>(x, W, ws_part, ntiles);
        router_stats4<<<nstat, 1024, 0, stream>>>(ws_part, out, ws_prob, ws_z, ws_cnt, Ntok);
        router_final2<<<1, 256, 0, stream>>>(ws_prob, ws_z, ws_cnt, out, Ntok, nstat);
    } else {
        const int nb = Ntok / 64;
        float* ws_prob = (float*)d_ws;
        float* ws_z    = ws_prob + (size_t)nb * NE;
        int*   ws_cnt  = (int*)(ws_z + nb);
        router_main_fb<<<nb, 256, 0, stream>>>(x, W, out, ws_prob, ws_z, ws_cnt, Ntok);
        router_final_kernel:
        router_final2<<<1, 256, 0, stream>>>(ws_prob, ws_z, ws_cnt, out, Ntok, nb);
    }
}

// Round 11
// 88.184 us; speedup vs baseline: 2.6918x; 1.4399x over previous
//
#include <hip/hip_runtime.h>
#include <math.h>

#define D_MODEL 2048
#define NE      64
#define TB      64               // tokens per gemm block
#define KS      2                // split-K
#define KSEG    (D_MODEL / KS)   // 1024
#define KC      128              // fp32 k per chunk
#define NCH     (KSEG / KC)      // 8
#define FB_KC   32
#define FB_NCH  (D_MODEL / FB_KC)

typedef _Float16 half8 __attribute__((ext_vector_type(8)));
typedef float    f32x4 __attribute__((ext_vector_type(4)));

// ---------------- W -> (Wh, Wl) fp16 split, scaled x64 ----------------------
// w' = 64w = wh + wl with wh=f16(w'), wl=f16(w'-wh). 64x makes wl normal
// (fp16 min normal 6.1e-5) for |w|>2e-3; smaller w contribute ~nothing.
__global__ __launch_bounds__(256) void wcvt_kernel(
    const float* __restrict__ W, short* __restrict__ Wh, short* __restrict__ Wl)
{
    const int e = blockIdx.x, t = threadIdx.x, c = t * 8;
    const float* src = W + (size_t)e * D_MODEL + c;
    float4 v0 = *(const float4*)src;
    float4 v1 = *(const float4*)(src + 4);
    float vs[8] = {v0.x, v0.y, v0.z, v0.w, v1.x, v1.y, v1.z, v1.w};
    union { _Float16 h[8]; uint4 u; } hs, ls;
    #pragma unroll
    for (int i = 0; i < 8; ++i) {
        float w = vs[i] * 64.0f;
        _Float16 h = (_Float16)w;
        hs.h[i] = h;
        ls.h[i] = (_Float16)(w - (float)h);
    }
    *(uint4*)&Wh[(size_t)e * D_MODEL + c] = hs.u;
    *(uint4*)&Wl[(size_t)e * D_MODEL + c] = ls.u;
}

// ---------------- split-K MFMA GEMM: 64 tok x 64 exp x KSEG -----------------
// logits*512 = (8x)(64w) = xh*wh + xh*wl + xl*wh + xl*wl -> 4 mfma/k-step.
// A: global fp32 -> reg (prefetched during prev MFMA phase) -> cvt -> LDS f16.
// W: Wh/Wl global (L2-hot) -> reg -> LDS. All in-loop loads are ds_read
// (in-order lgkm, counted waits). LDS XOR-swizzle both sides: row r slot s
// stored at s^(r&7) (16B granule) -> reads 2-way max (free, m136).
__global__ __launch_bounds__(256, 2) void router_mfma(
    const float* __restrict__ x, const short* __restrict__ Whg,
    const short* __restrict__ Wlg, float* __restrict__ part, int ntiles)
{
    __shared__ __align__(16) char smem[65536];
    short* Ah = (short*)smem;                 // [64][128] f16, swizzled
    short* Al = (short*)(smem + 16384);
    short* Wh = (short*)(smem + 32768);
    short* Wl = (short*)(smem + 49152);

    const int t    = threadIdx.x;
    const int tile = blockIdx.x;
    const int ks   = blockIdx.y;
    const int m0   = tile * TB;
    const int k0   = ks * KSEG;               // in elements (fp32 or f16)
    const int l    = t & 63;
    const int wv   = t >> 6;                  // 0..3

    // staging map (A rows == W rows): item i (0..3): row = i*16 + (t>>4),
    // 16B slot = t&15; swizzled dest slot = (t&15) ^ ((t>>4)&7)
    const int srow = t >> 4;                  // 0..15
    const int sslt = t & 15;
    const int sw   = srow & 7;
    const int soff0 = ((sslt ^ sw) << 3);     // halves within row

    float4 pa[8];                             // A prefetch: 4 rows x 8 floats
    uint4  pw[8];                             // W prefetch: 4 rows x (Wh,Wl)

    // prologue: prefetch chunk 0
    #pragma unroll
    for (int i = 0; i < 4; ++i) {
        const float* ap = x + (size_t)(m0 + i * 16 + srow) * D_MODEL + k0 + sslt * 8;
        pa[2 * i]     = *(const float4*)ap;
        pa[2 * i + 1] = *(const float4*)(ap + 4);
        const size_t wrow = (size_t)(i * 16 + srow) * D_MODEL + k0 + sslt * 8;
        pw[i]     = *(const uint4*)&Whg[wrow];
        pw[i + 4] = *(const uint4*)&Wlg[wrow];
    }

    f32x4 acc[4] = {{0.f,0.f,0.f,0.f},{0.f,0.f,0.f,0.f},
                    {0.f,0.f,0.f,0.f},{0.f,0.f,0.f,0.f}};

    for (int ch = 0; ch < NCH; ++ch) {
        __builtin_amdgcn_s_barrier();         // prev MFMA phase done with LDS
        // convert + write A (8 halves -> one b128 per row-item), write W
        #pragma unroll
        for (int i = 0; i < 4; ++i) {
            union { _Float16 h[8]; uint4 u; } hh, ll;
            float va[8] = {pa[2*i].x, pa[2*i].y, pa[2*i].z, pa[2*i].w,
                           pa[2*i+1].x, pa[2*i+1].y, pa[2*i+1].z, pa[2*i+1].w};
            #pragma unroll
            for (int j = 0; j < 8; ++j) {
                float xs = va[j] * 8.0f;
                _Float16 h = (_Float16)xs;
                hh.h[j] = h;
                ll.h[j] = (_Float16)(xs - (float)h);
            }
            const int off = (i * 16 + srow) * 128 + soff0;
            *(uint4*)&Ah[off] = hh.u;
            *(uint4*)&Al[off] = ll.u;
            *(uint4*)&Wh[off] = pw[i];
            *(uint4*)&Wl[off] = pw[i + 4];
        }
        __builtin_amdgcn_s_barrier();         // LDS ready
        if (ch + 1 < NCH) {                   // prefetch next chunk (flies
            const int kb = k0 + (ch + 1) * KC;            // under MFMA phase)
            #pragma unroll
            for (int i = 0; i < 4; ++i) {
                const float* ap = x + (size_t)(m0 + i * 16 + srow) * D_MODEL + kb + sslt * 8;
                pa[2 * i]     = *(const float4*)ap;
                pa[2 * i + 1] = *(const float4*)(ap + 4);
                const size_t wrow = (size_t)(i * 16 + srow) * D_MODEL + kb + sslt * 8;
                pw[i]     = *(const uint4*)&Whg[wrow];
                pw[i + 4] = *(const uint4*)&Wlg[wrow];
            }
        }
        // MFMA phase: wave wv owns token rows wv*16..+15, all 64 experts
        const int arow = wv * 16 + (l & 15);
        const int rsw  = l & 7;               // == row&7 for A and W reads
        #pragma unroll
        for (int kq = 0; kq < 4; ++kq) {
            const int s    = kq * 4 + (l >> 4);
            const int aoff = arow * 128 + ((s ^ rsw) << 3);
            half8 ah = *(const half8*)&Ah[aoff];
            half8 al = *(const half8*)&Al[aoff];
            #pragma unroll
            for (int n = 0; n < 4; ++n) {
                const int woff = (n * 16 + (l & 15)) * 128 + ((s ^ rsw) << 3);
                half8 wh = *(const half8*)&Wh[woff];
                half8 wl = *(const half8*)&Wl[woff];
                acc[n] = __builtin_amdgcn_mfma_f32_16x16x32_f16(al, wl, acc[n], 0, 0, 0);
                acc[n] = __builtin_amdgcn_mfma_f32_16x16x32_f16(al, wh, acc[n], 0, 0, 0);
                acc[n] = __builtin_amdgcn_mfma_f32_16x16x32_f16(ah, wl, acc[n], 0, 0, 0);
                acc[n] = __builtin_amdgcn_mfma_f32_16x16x32_f16(ah, wh, acc[n], 0, 0, 0);
            }
        }
    }

    // partials [tile][ks][row 64][e 64], scaled back by 1/512 (exact pow2)
    float* dst = part + ((size_t)tile * KS + ks) * (TB * NE);
    #pragma unroll
    for (int n = 0; n < 4; ++n)
        #pragma unroll
        for (int q = 0; q < 4; ++q) {
            const int row = wv * 16 + (l >> 4) * 4 + q;   // D: row=(l>>4)*4+reg
            const int col = n * 16 + (l & 15);            //    col=l&15 (m89)
            dst[row * NE + col] = acc[n][q] * (1.0f / 512.0f);
        }
}

// ---------------- sum KS partials + fused stats, 1024 thr (proven phases) ---
__global__ __launch_bounds__(1024) void router_stats5(
    const float* __restrict__ part, float* __restrict__ out,
    float* __restrict__ ws_prob, float* __restrict__ ws_z,
    int* __restrict__ ws_cnt, int Ntok)
{
    __shared__ float sL[64][NE + 1];
    __shared__ float red16[64][16];
    __shared__ int   arg16[64][16];
    __shared__ float smax[64], sinv[64];
    __shared__ float spart[16][NE];
    __shared__ int   hist[NE];

    const int t = threadIdx.x, b = blockIdx.x, m0 = b * 64;
    const float* base = part + (size_t)b * KS * (TB * NE);

    {   // sum KS partials: thread t owns float4 #t (fixed order: deterministic)
        const float* p0 = base + (size_t)t * 4;
        float s0 = 0.f, s1 = 0.f, s2 = 0.f, s3 = 0.f;
        #pragma unroll
        for (int j = 0; j < KS; ++j) {
            float4 v = *(const float4*)(p0 + (size_t)j * (TB * NE));
            s0 += v.x; s1 += v.y; s2 += v.z; s3 += v.w;
        }
        const int row = t >> 4, col = (t & 15) << 2;
        sL[row][col]     = s0; sL[row][col + 1] = s1;
        sL[row][col + 2] = s2; sL[row][col + 3] = s3;
    }
    if (t < NE) hist[t] = 0;
    __syncthreads();

    {   // argmax: 16 threads/token, 4 experts each (ascending -> first-max ok)
        const int m = t >> 4, qr = t & 15;
        float mx = -3.4e38f; int ag = qr * 4;
        #pragma unroll
        for (int k = 0; k < 4; ++k) {
            const int e = qr * 4 + k;
            float v = sL[m][e];
            if (v > mx) { mx = v; ag = e; }
        }
        red16[m][qr] = mx; arg16[m][qr] = ag;
    }
    __syncthreads();
    if (t < 64) {                            // combine ascending: first-max kept
        const int m = t;
        float mx = red16[m][0]; int ag = arg16[m][0];
        #pragma unroll
        for (int qr = 1; qr < 16; ++qr)
            if (red16[m][qr] > mx) { mx = red16[m][qr]; ag = arg16[m][qr]; }
        smax[m] = mx;
        out[m0 + m] = (float)ag;             // expert_index
        atomicAdd(&hist[ag], 1);
    }
    __syncthreads();
    {   // expsum: 16 threads/token
        const int m = t >> 4, qr = t & 15;
        const float mx = smax[m];
        float s = 0.f;
        #pragma unroll
        for (int k = 0; k < 4; ++k) s += expf(sL[m][qr * 4 + k] - mx);
        red16[m][qr] = s;
    }
    __syncthreads();
    if (t < 64) {
        const int m = t;
        float s = 0.f;
        #pragma unroll
        for (int qr = 0; qr < 16; ++qr) s += red16[m][qr];   // fixed order
        float inv = 1.f / s;
        sinv[m] = inv;
        out[Ntok + m0 + m] = inv;            // expert_prob
        float lse = smax[m] + logf(s);
        float z = lse * lse;
        #pragma unroll
        for (int off = 32; off > 0; off >>= 1) z += __shfl_down(z, off, 64);
        if (t == 0) ws_z[b] = z;
    }
    __syncthreads();
    {   // probsum: 16 waves, wave g covers 4 tokens, lane = expert
        const int e = t & 63, g = t >> 6;
        float pa = 0.f;
        #pragma unroll
        for (int k = 0; k < 4; ++k) {
            const int m = g * 4 + k;
            pa += expf(sL[m][e] - smax[m]) * sinv[m];
        }
        spart[g][e] = pa;
    }
    __syncthreads();
    if (t < NE) {
        float ps = 0.f;
        #pragma unroll
        for (int g = 0; g < 16; ++g) ps += spart[g][t];      // fixed order
        ws_prob[b * NE + t] = ps;
        ws_cnt[b * NE + t]  = hist[t];
    }
}

// ---------------- final reduce (r10 parallel version, proven) ---------------
__global__ __launch_bounds__(256) void router_final2(
    const float* __restrict__ ws_prob, const float* __restrict__ ws_z,
    const int* __restrict__ ws_cnt, float* __restrict__ out,
    int Ntok, int nblocks)
{
    __shared__ float sp[4][NE];
    __shared__ int   sc[4][NE];
    __shared__ float sz[4];

    const int e = threadIdx.x & 63, g = threadIdx.x >> 6;
    const int per = nblocks / 4;
    const int hi  = (g == 3) ? nblocks : (g + 1) * per;

    float ps = 0.f; int c = 0;
    for (int blk = g * per; blk < hi; ++blk) {       // fixed partition: determ.
        ps += ws_prob[blk * NE + e];
        c  += ws_cnt[blk * NE + e];
    }
    sp[g][e] = ps; sc[g][e] = c;

    float z = 0.f;
    for (int blk = (int)threadIdx.x; blk < nblocks; blk += 256) z += ws_z[blk];
    #pragma unroll
    for (int off = 32; off > 0; off >>= 1) z += __shfl_down(z, off, 64);
    if (e == 0) sz[g] = z;
    __syncthreads();

    if (threadIdx.x < 64) {
        const int ee = threadIdx.x;
        float pst = ((sp[0][ee] + sp[1][ee]) + sp[2][ee]) + sp[3][ee];
        int   ct  = ((sc[0][ee] + sc[1][ee]) + sc[2][ee]) + sc[3][ee];
        out[2 * Ntok + ee] = (float)ct;              // counts

        float fN = (float)Ntok;
        float fp = ((float)ct / fN) * (pst / fN);
        #pragma unroll
        for (int off = 32; off > 0; off >>= 1) fp += __shfl_down(fp, off, 64);
        if (ee == 0) {
            float zt = ((sz[0] + sz[1]) + sz[2]) + sz[3];
            int cap = (Ntok + NE - 1) / NE;
            if (cap < 4) cap = 4;
            float aux = 0.01f * (float)NE * fp + 1e-3f * (zt / fN);
            out[2 * Ntok + NE]     = (float)cap;     // capacity
            out[2 * Ntok + NE + 1] = aux;            // aux_loss
        }
    }
}

// ---------------- fallback (round-1 proven fused fp32 path) -----------------
__global__ __launch_bounds__(256) void router_main_fb(
    const float* __restrict__ x, const float* __restrict__ W,
    float* __restrict__ out, float* __restrict__ ws_prob,
    float* __restrict__ ws_z, int* __restrict__ ws_cnt, int Ntok)
{
    __shared__ __align__(16) float sX[FB_KC][68];
    __shared__ __align__(16) float sW[FB_KC][68];
    __shared__ float sL[64][65];
    __shared__ float smax[64], sinv[64];
    __shared__ float spart[4][NE];
    __shared__ int   hist[NE];

    const int t = threadIdx.x, b = blockIdx.x, m0 = b * 64;
    const int mq = t & 15, nq = t >> 4;
    const int r1 = t >> 3, r2 = r1 + 32, c1 = (t & 7) << 2;
    const float* xp1 = x + (size_t)(m0 + r1) * D_MODEL + c1;
    const float* xp2 = x + (size_t)(m0 + r2) * D_MODEL + c1;
    const float* wp1 = W + (size_t)r1 * D_MODEL + c1;
    const float* wp2 = W + (size_t)r2 * D_MODEL + c1;
    float4 ax1 = *(const float4*)xp1, ax2 = *(const float4*)xp2;
    float4 aw1 = *(const float4*)wp1, aw2 = *(const float4*)wp2;
    float a1[4][4] = {}, a2[4][4] = {};
    for (int ch = 0; ch < FB_NCH; ++ch) {
        __syncthreads();
        sX[c1+0][r1] = ax1.x; sX[c1+1][r1] = ax1.y; sX[c1+2][r1] = ax1.z; sX[c1+3][r1] = ax1.w;
        sX[c1+0][r2] = ax2.x; sX[c1+1][r2] = ax2.y; sX[c1+2][r2] = ax2.z; sX[c1+3][r2] = ax2.w;
        sW[c1+0][r1] = aw1.x; sW[c1+1][r1] = aw1.y; sW[c1+2][r1] = aw1.z; sW[c1+3][r1] = aw1.w;
        sW[c1+0][r2] = aw2.x; sW[c1+1][r2] = aw2.y; sW[c1+2][r2] = aw2.z; sW[c1+3][r2] = aw2.w;
        __syncthreads();
        if (ch + 1 < FB_NCH) {
            xp1 += FB_KC; xp2 += FB_KC; wp1 += FB_KC; wp2 += FB_KC;
            ax1 = *(const float4*)xp1; ax2 = *(const float4*)xp2;
            aw1 = *(const float4*)wp1; aw2 = *(const float4*)wp2;
        }
        #pragma unroll
        for (int k = 0; k < FB_KC; ++k) {
            float4 xa = *(const float4*)&sX[k][mq << 2];
            float4 wb = *(const float4*)&sW[k][nq << 2];
            float (*A)[4] = (k < FB_KC / 2) ? a1 : a2;
            A[0][0] = fmaf(xa.x, wb.x, A[0][0]); A[0][1] = fmaf(xa.x, wb.y, A[0][1]);
            A[0][2] = fmaf(xa.x, wb.z, A[0][2]); A[0][3] = fmaf(xa.x, wb.w, A[0][3]);
            A[1][0] = fmaf(xa.y, wb.x, A[1][0]); A[1][1] = fmaf(xa.y, wb.y, A[1][1]);
            A[1][2] = fmaf(xa.y, wb.z, A[1][2]); A[1][3] = fmaf(xa.y, wb.w, A[1][3]);
            A[2][0] = fmaf(xa.z, wb.x, A[2][0]); A[2][1] = fmaf(xa.z, wb.y, A[2][1]);
            A[2][2] = fmaf(xa.z, wb.z, A[2][2]); A[2][3] = fmaf(xa.z, wb.w, A[2][3]);
            A[3][0] = fmaf(xa.w, wb.x, A[3][0]); A[3][1] = fmaf(xa.w, wb.y, A[3][1]);
            A[3][2] = fmaf(xa.w, wb.z, A[3][2]); A[3][3] = fmaf(xa.w, wb.w, A[3][3]);
        }
    }
    #pragma unroll
    for (int i = 0; i < 4; ++i)
        #pragma unroll
        for (int j = 0; j < 4; ++j)
            sL[(mq << 2) + i][(nq << 2) + j] = a1[i][j] + a2[i][j];
    if (t < NE) hist[t] = 0;
    __syncthreads();
    if (t < 64) {
        const int m = t;
        float mx = sL[m][0]; int arg = 0;
        for (int e = 1; e < NE; ++e) { float v = sL[m][e]; if (v > mx) { mx = v; arg = e; } }
        float s = 0.f;
        for (int e = 0; e < NE; ++e) s += expf(sL[m][e] - mx);
        float inv = 1.f / s;
        out[m0 + m] = (float)arg; out[Ntok + m0 + m] = inv;
        smax[m] = mx; sinv[m] = inv;
        atomicAdd(&hist[arg], 1);
        float lse = mx + logf(s); float z = lse * lse;
        for (int off = 32; off > 0; off >>= 1) z += __shfl_down(z, off, 64);
        if (t == 0) ws_z[b] = z;
    }
    __syncthreads();
    {
        const int e = t & 63, mg = t >> 6;
        float pa = 0.f;
        for (int m = mg * 16; m < mg * 16 + 16; ++m) pa += expf(sL[m][e] - smax[m]) * sinv[m];
        spart[mg][e] = pa;
    }
    __syncthreads();
    if (t < NE) {
        ws_prob[b * NE + t] = spart[0][t] + spart[1][t] + spart[2][t] + spart[3][t];
        ws_cnt[b * NE + t]  = hist[t];
    }
}

extern "C" void kernel_launch(void* const* d_in, const int* in_sizes, int n_in,
                              void* d_out, int out_size, void* d_ws, size_t ws_size,
                              hipStream_t stream)
{
    const float* x = (const float*)d_in[0];
    const float* W = (const float*)d_in[1];
    float* out = (float*)d_out;

    const int Ntok   = in_sizes[0] / D_MODEL;        // 16384
    const int ntiles = Ntok / TB;                    // 256
    const int nstat  = Ntok / 64;                    // 256

    const size_t wh_elems   = (size_t)NE * D_MODEL;              // 131072 shorts
    const size_t part_elems = (size_t)ntiles * KS * TB * NE;     // 2.1M floats
    const size_t need = wh_elems * 2 * 2                          // Wh+Wl bytes
                      + (part_elems + (size_t)nstat * NE + nstat) * 4
                      + (size_t)nstat * NE * 4 + 1024;

    if ((Ntok % TB) == 0 && ws_size >= need) {
        short* wsh    = (short*)d_ws;                // Wh [64][2048]
        short* wsl    = wsh + wh_elems;              // Wl
        float* ws_part = (float*)(wsl + wh_elems);
        float* ws_prob = ws_part + part_elems;
        float* ws_z    = ws_prob + (size_t)nstat * NE;
        int*   ws_cnt  = (int*)(ws_z + nstat);

        wcvt_kernel<<<NE, 256, 0, stream>>>(W, wsh, wsl);
        dim3 grid(ntiles, KS);
        router_mfma<<<grid, 256, 0, stream>>>(x, wsh, wsl, ws_part, ntiles);
        router_stats5<<<nstat, 1024, 0, stream>>>(ws_part, out, ws_prob, ws_z, ws_cnt, Ntok);
        router_final2<<<1, 256, 0, stream>>>(ws_prob, ws_z, ws_cnt, out, Ntok, nstat);
    } else {
        const int nb = Ntok / 64;
        float* ws_prob = (float*)d_ws;
        float* ws_z    = ws_prob + (size_t)nb * NE;
        int*   ws_cnt  = (int*)(ws_z + nb);
        router_main_fb<<<nb, 256, 0, stream>>>(x, W, out, ws_prob, ws_z, ws_cnt, Ntok);
        router_final2<<<1, 256, 0, stream>>>(ws_prob, ws_z, ws_cnt, out, Ntok, nb);
    }
}

// Round 12
// 61.604 us; speedup vs baseline: 3.8531x; 1.4315x over previous
//
#include <hip/hip_runtime.h>
#include <math.h>

#define D_MODEL 2048
#define NE      64
#define TB      64               // tokens per gemm block
#define KS      2                // split-K
#define KSEG    (D_MODEL / KS)   // 1024
#define KC      128              // fp32 k per chunk
#define NCH     (KSEG / KC)      // 8
#define FB_KC   32
#define FB_NCH  (D_MODEL / FB_KC)

typedef _Float16 half8 __attribute__((ext_vector_type(8)));
typedef float    f32x4 __attribute__((ext_vector_type(4)));

// two-term split of one float into fp16 high+low at ext-vector slot J.
// Named vars + constant indices only: NO unions / private arrays (rule #20 —
// r11's union/array conversion went to scratch: 91MB WRITE, both pipes idle).
#define CVT1(F, HV, LV, J) do {                                               \
    float _f = (F);                                                           \
    _Float16 _h = (_Float16)_f;                                               \
    HV[J] = _h;                                                               \
    LV[J] = (_Float16)(_f - (float)_h);                                       \
} while (0)

// ---------------- W -> (Wh, Wl) fp16 split, scaled x64 ----------------------
__global__ __launch_bounds__(256) void wcvt_kernel(
    const float* __restrict__ W, short* __restrict__ Wh, short* __restrict__ Wl)
{
    const int e = blockIdx.x, t = threadIdx.x, c = t * 8;
    const float* src = W + (size_t)e * D_MODEL + c;
    float4 v0 = *(const float4*)src;
    float4 v1 = *(const float4*)(src + 4);
    half8 hv, lv;
    CVT1(v0.x * 64.0f, hv, lv, 0); CVT1(v0.y * 64.0f, hv, lv, 1);
    CVT1(v0.z * 64.0f, hv, lv, 2); CVT1(v0.w * 64.0f, hv, lv, 3);
    CVT1(v1.x * 64.0f, hv, lv, 4); CVT1(v1.y * 64.0f, hv, lv, 5);
    CVT1(v1.z * 64.0f, hv, lv, 6); CVT1(v1.w * 64.0f, hv, lv, 7);
    *(half8*)(Wh + (size_t)e * D_MODEL + c) = hv;
    *(half8*)(Wl + (size_t)e * D_MODEL + c) = lv;
}

// ---------------- split-K MFMA GEMM: 64 tok x 64 exp x KSEG -----------------
// logits*512 = (8x)(64w) = xh*wh + xh*wl + xl*wh + xl*wl -> 4 mfma/k-step.
// Structure identical to r11 (passed, absmax 2.4e-4); only the conversion
// codegen changed (scratch-free). LDS XOR-swizzle both sides (r11-proven).
__global__ __launch_bounds__(256, 2) void router_mfma(
    const float* __restrict__ x, const short* __restrict__ Whg,
    const short* __restrict__ Wlg, float* __restrict__ part, int ntiles)
{
    __shared__ __align__(16) char smem[65536];
    _Float16* Ah = (_Float16*)smem;           // [64][128] f16, swizzled
    _Float16* Al = (_Float16*)(smem + 16384);
    _Float16* Wh = (_Float16*)(smem + 32768);
    _Float16* Wl = (_Float16*)(smem + 49152);

    const int t    = threadIdx.x;
    const int tile = blockIdx.x;
    const int ks   = blockIdx.y;
    const int m0   = tile * TB;
    const int k0   = ks * KSEG;
    const int l    = t & 63;
    const int wv   = t >> 6;                  // 0..3

    // staging map: item i (0..3): row = i*16 + (t>>4), 16B slot = t&15;
    // swizzled dest slot = (t&15) ^ ((t>>4)&7)
    const int srow = t >> 4;                  // 0..15
    const int sslt = t & 15;
    const int soff0 = ((sslt ^ (srow & 7)) << 3);

    // A prefetch: 4 rows x 8 floats; W prefetch: 4 rows x (Wh,Wl) 16B each.
    // All statically indexed (unrolled) -> registers.
    float4 pa0, pa1, pa2, pa3, pa4, pa5, pa6, pa7;
    uint4  pwh0, pwh1, pwh2, pwh3, pwl0, pwl1, pwl2, pwl3;

#define PREFETCH(KB) do {                                                     \
    const float* _ap0 = x + (size_t)(m0 +  0 + srow) * D_MODEL + (KB) + sslt * 8; \
    const float* _ap1 = x + (size_t)(m0 + 16 + srow) * D_MODEL + (KB) + sslt * 8; \
    const float* _ap2 = x + (size_t)(m0 + 32 + srow) * D_MODEL + (KB) + sslt * 8; \
    const float* _ap3 = x + (size_t)(m0 + 48 + srow) * D_MODEL + (KB) + sslt * 8; \
    pa0 = *(const float4*)_ap0; pa1 = *(const float4*)(_ap0 + 4);             \
    pa2 = *(const float4*)_ap1; pa3 = *(const float4*)(_ap1 + 4);             \
    pa4 = *(const float4*)_ap2; pa5 = *(const float4*)(_ap2 + 4);             \
    pa6 = *(const float4*)_ap3; pa7 = *(const float4*)(_ap3 + 4);             \
    const size_t _w0 = (size_t)( 0 + srow) * D_MODEL + (KB) + sslt * 8;       \
    const size_t _w1 = (size_t)(16 + srow) * D_MODEL + (KB) + sslt * 8;       \
    const size_t _w2 = (size_t)(32 + srow) * D_MODEL + (KB) + sslt * 8;       \
    const size_t _w3 = (size_t)(48 + srow) * D_MODEL + (KB) + sslt * 8;       \
    pwh0 = *(const uint4*)&Whg[_w0]; pwh1 = *(const uint4*)&Whg[_w1];         \
    pwh2 = *(const uint4*)&Whg[_w2]; pwh3 = *(const uint4*)&Whg[_w3];         \
    pwl0 = *(const uint4*)&Wlg[_w0]; pwl1 = *(const uint4*)&Wlg[_w1];         \
    pwl2 = *(const uint4*)&Wlg[_w2]; pwl3 = *(const uint4*)&Wlg[_w3];         \
} while (0)

// convert pa{A},pa{B} (8 floats, x8 scale) -> half8 pair; store A+W row item I
#define STORE_ITEM(I, PA, PB, PWH, PWL) do {                                  \
    half8 _hv, _lv;                                                           \
    CVT1((PA).x * 8.0f, _hv, _lv, 0); CVT1((PA).y * 8.0f, _hv, _lv, 1);       \
    CVT1((PA).z * 8.0f, _hv, _lv, 2); CVT1((PA).w * 8.0f, _hv, _lv, 3);       \
    CVT1((PB).x * 8.0f, _hv, _lv, 4); CVT1((PB).y * 8.0f, _hv, _lv, 5);       \
    CVT1((PB).z * 8.0f, _hv, _lv, 6); CVT1((PB).w * 8.0f, _hv, _lv, 7);       \
    const int _off = ((I) * 16 + srow) * 128 + soff0;                         \
    *(half8*)&Ah[_off] = _hv;                                                 \
    *(half8*)&Al[_off] = _lv;                                                 \
    *(uint4*)&Wh[_off] = PWH;                                                 \
    *(uint4*)&Wl[_off] = PWL;                                                 \
} while (0)

    PREFETCH(k0);                             // chunk 0

    f32x4 acc0 = {0.f,0.f,0.f,0.f}, acc1 = {0.f,0.f,0.f,0.f};
    f32x4 acc2 = {0.f,0.f,0.f,0.f}, acc3 = {0.f,0.f,0.f,0.f};

    for (int ch = 0; ch < NCH; ++ch) {
        __builtin_amdgcn_s_barrier();         // prev MFMA phase done with LDS
        STORE_ITEM(0, pa0, pa1, pwh0, pwl0);
        STORE_ITEM(1, pa2, pa3, pwh1, pwl1);
        STORE_ITEM(2, pa4, pa5, pwh2, pwl2);
        STORE_ITEM(3, pa6, pa7, pwh3, pwl3);
        __builtin_amdgcn_s_barrier();         // LDS ready
        if (ch + 1 < NCH)                     // next chunk flies under MFMA
            PREFETCH(k0 + (ch + 1) * KC);

        // MFMA phase: wave wv owns token rows wv*16..+15, all 64 experts
        const int arow = wv * 16 + (l & 15);
        const int rsw  = l & 7;
        #pragma unroll
        for (int kq = 0; kq < 4; ++kq) {
            const int s    = kq * 4 + (l >> 4);
            const int aoff = arow * 128 + ((s ^ rsw) << 3);
            half8 ah = *(const half8*)&Ah[aoff];
            half8 al = *(const half8*)&Al[aoff];
            #pragma unroll
            for (int n = 0; n < 4; ++n) {
                const int woff = (n * 16 + (l & 15)) * 128 + ((s ^ rsw) << 3);
                half8 wh = *(const half8*)&Wh[woff];
                half8 wl = *(const half8*)&Wl[woff];
                f32x4 a = (n == 0) ? acc0 : (n == 1) ? acc1 : (n == 2) ? acc2 : acc3;
                a = __builtin_amdgcn_mfma_f32_16x16x32_f16(al, wl, a, 0, 0, 0);
                a = __builtin_amdgcn_mfma_f32_16x16x32_f16(al, wh, a, 0, 0, 0);
                a = __builtin_amdgcn_mfma_f32_16x16x32_f16(ah, wl, a, 0, 0, 0);
                a = __builtin_amdgcn_mfma_f32_16x16x32_f16(ah, wh, a, 0, 0, 0);
                if (n == 0) acc0 = a; else if (n == 1) acc1 = a;
                else if (n == 2) acc2 = a; else acc3 = a;
            }
        }
    }

    // partials [tile][ks][row 64][e 64], scaled back by 1/512 (exact pow2)
    // D layout: col=l&15, row=(l>>4)*4+reg (m89-verified, r11-passed)
    float* dst = part + ((size_t)tile * KS + ks) * (TB * NE);
    const int rbase = wv * 16 + (l >> 4) * 4;
    const int col0  = l & 15;
    #pragma unroll
    for (int q = 0; q < 4; ++q) {
        dst[(rbase + q) * NE +  0 + col0] = acc0[q] * (1.0f / 512.0f);
        dst[(rbase + q) * NE + 16 + col0] = acc1[q] * (1.0f / 512.0f);
        dst[(rbase + q) * NE + 32 + col0] = acc2[q] * (1.0f / 512.0f);
        dst[(rbase + q) * NE + 48 + col0] = acc3[q] * (1.0f / 512.0f);
    }
}

// ---------------- sum KS partials + fused stats, 1024 thr (proven phases) ---
__global__ __launch_bounds__(1024) void router_stats5(
    const float* __restrict__ part, float* __restrict__ out,
    float* __restrict__ ws_prob, float* __restrict__ ws_z,
    int* __restrict__ ws_cnt, int Ntok)
{
    __shared__ float sL[64][NE + 1];
    __shared__ float red16[64][16];
    __shared__ int   arg16[64][16];
    __shared__ float smax[64], sinv[64];
    __shared__ float spart[16][NE];
    __shared__ int   hist[NE];

    const int t = threadIdx.x, b = blockIdx.x, m0 = b * 64;
    const float* base = part + (size_t)b * KS * (TB * NE);

    {   // sum KS partials: thread t owns float4 #t (fixed order: deterministic)
        const float* p0 = base + (size_t)t * 4;
        float s0 = 0.f, s1 = 0.f, s2 = 0.f, s3 = 0.f;
        #pragma unroll
        for (int j = 0; j < KS; ++j) {
            float4 v = *(const float4*)(p0 + (size_t)j * (TB * NE));
            s0 += v.x; s1 += v.y; s2 += v.z; s3 += v.w;
        }
        const int row = t >> 4, col = (t & 15) << 2;
        sL[row][col]     = s0; sL[row][col + 1] = s1;
        sL[row][col + 2] = s2; sL[row][col + 3] = s3;
    }
    if (t < NE) hist[t] = 0;
    __syncthreads();

    {   // argmax: 16 threads/token, 4 experts each (ascending -> first-max ok)
        const int m = t >> 4, qr = t & 15;
        float mx = -3.4e38f; int ag = qr * 4;
        #pragma unroll
        for (int k = 0; k < 4; ++k) {
            const int e = qr * 4 + k;
            float v = sL[m][e];
            if (v > mx) { mx = v; ag = e; }
        }
        red16[m][qr] = mx; arg16[m][qr] = ag;
    }
    __syncthreads();
    if (t < 64) {                            // combine ascending: first-max kept
        const int m = t;
        float mx = red16[m][0]; int ag = arg16[m][0];
        #pragma unroll
        for (int qr = 1; qr < 16; ++qr)
            if (red16[m][qr] > mx) { mx = red16[m][qr]; ag = arg16[m][qr]; }
        smax[m] = mx;
        out[m0 + m] = (float)ag;             // expert_index
        atomicAdd(&hist[ag], 1);
    }
    __syncthreads();
    {   // expsum: 16 threads/token
        const int m = t >> 4, qr = t & 15;
        const float mx = smax[m];
        float s = 0.f;
        #pragma unroll
        for (int k = 0; k < 4; ++k) s += expf(sL[m][qr * 4 + k] - mx);
        red16[m][qr] = s;
    }
    __syncthreads();
    if (t < 64) {
        const int m = t;
        float s = 0.f;
        #pragma unroll
        for (int qr = 0; qr < 16; ++qr) s += red16[m][qr];   // fixed order
        float inv = 1.f / s;
        sinv[m] = inv;
        out[Ntok + m0 + m] = inv;            // expert_prob
        float lse = smax[m] + logf(s);
        float z = lse * lse;
        #pragma unroll
        for (int off = 32; off > 0; off >>= 1) z += __shfl_down(z, off, 64);
        if (t == 0) ws_z[b] = z;
    }
    __syncthreads();
    {   // probsum: 16 waves, wave g covers 4 tokens, lane = expert
        const int e = t & 63, g = t >> 6;
        float pa = 0.f;
        #pragma unroll
        for (int k = 0; k < 4; ++k) {
            const int m = g * 4 + k;
            pa += expf(sL[m][e] - smax[m]) * sinv[m];
        }
        spart[g][e] = pa;
    }
    __syncthreads();
    if (t < NE) {
        float ps = 0.f;
        #pragma unroll
        for (int g = 0; g < 16; ++g) ps += spart[g][t];      // fixed order
        ws_prob[b * NE + t] = ps;
        ws_cnt[b * NE + t]  = hist[t];
    }
}

// ---------------- final reduce (r10 parallel version, proven) ---------------
__global__ __launch_bounds__(256) void router_final2(
    const float* __restrict__ ws_prob, const float* __restrict__ ws_z,
    const int* __restrict__ ws_cnt, float* __restrict__ out,
    int Ntok, int nblocks)
{
    __shared__ float sp[4][NE];
    __shared__ int   sc[4][NE];
    __shared__ float sz[4];

    const int e = threadIdx.x & 63, g = threadIdx.x >> 6;
    const int per = nblocks / 4;
    const int hi  = (g == 3) ? nblocks : (g + 1) * per;

    float ps = 0.f; int c = 0;
    for (int blk = g * per; blk < hi; ++blk) {       // fixed partition: determ.
        ps += ws_prob[blk * NE + e];
        c  += ws_cnt[blk * NE + e];
    }
    sp[g][e] = ps; sc[g][e] = c;

    float z = 0.f;
    for (int blk = (int)threadIdx.x; blk < nblocks; blk += 256) z += ws_z[blk];
    #pragma unroll
    for (int off = 32; off > 0; off >>= 1) z += __shfl_down(z, off, 64);
    if (e == 0) sz[g] = z;
    __syncthreads();

    if (threadIdx.x < 64) {
        const int ee = threadIdx.x;
        float pst = ((sp[0][ee] + sp[1][ee]) + sp[2][ee]) + sp[3][ee];
        int   ct  = ((sc[0][ee] + sc[1][ee]) + sc[2][ee]) + sc[3][ee];
        out[2 * Ntok + ee] = (float)ct;              // counts

        float fN = (float)Ntok;
        float fp = ((float)ct / fN) * (pst / fN);
        #pragma unroll
        for (int off = 32; off > 0; off >>= 1) fp += __shfl_down(fp, off, 64);
        if (ee == 0) {
            float zt = ((sz[0] + sz[1]) + sz[2]) + sz[3];
            int cap = (Ntok + NE - 1) / NE;
            if (cap < 4) cap = 4;
            float aux = 0.01f * (float)NE * fp + 1e-3f * (zt / fN);
            out[2 * Ntok + NE]     = (float)cap;     // capacity
            out[2 * Ntok + NE + 1] = aux;            // aux_loss
        }
    }
}

// ---------------- fallback (round-1 proven fused fp32 path) -----------------
__global__ __launch_bounds__(256) void router_main_fb(
    const float* __restrict__ x, const float* __restrict__ W,
    float* __restrict__ out, float* __restrict__ ws_prob,
    float* __restrict__ ws_z, int* __restrict__ ws_cnt, int Ntok)
{
    __shared__ __align__(16) float sX[FB_KC][68];
    __shared__ __align__(16) float sW[FB_KC][68];
    __shared__ float sL[64][65];
    __shared__ float smax[64], sinv[64];
    __shared__ float spart[4][NE];
    __shared__ int   hist[NE];

    const int t = threadIdx.x, b = blockIdx.x, m0 = b * 64;
    const int mq = t & 15, nq = t >> 4;
    const int r1 = t >> 3, r2 = r1 + 32, c1 = (t & 7) << 2;
    const float* xp1 = x + (size_t)(m0 + r1) * D_MODEL + c1;
    const float* xp2 = x + (size_t)(m0 + r2) * D_MODEL + c1;
    const float* wp1 = W + (size_t)r1 * D_MODEL + c1;
    const float* wp2 = W + (size_t)r2 * D_MODEL + c1;
    float4 ax1 = *(const float4*)xp1, ax2 = *(const float4*)xp2;
    float4 aw1 = *(const float4*)wp1, aw2 = *(const float4*)wp2;
    float a1[4][4] = {}, a2[4][4] = {};
    for (int ch = 0; ch < FB_NCH; ++ch) {
        __syncthreads();
        sX[c1+0][r1] = ax1.x; sX[c1+1][r1] = ax1.y; sX[c1+2][r1] = ax1.z; sX[c1+3][r1] = ax1.w;
        sX[c1+0][r2] = ax2.x; sX[c1+1][r2] = ax2.y; sX[c1+2][r2] = ax2.z; sX[c1+3][r2] = ax2.w;
        sW[c1+0][r1] = aw1.x; sW[c1+1][r1] = aw1.y; sW[c1+2][r1] = aw1.z; sW[c1+3][r1] = aw1.w;
        sW[c1+0][r2] = aw2.x; sW[c1+1][r2] = aw2.y; sW[c1+2][r2] = aw2.z; sW[c1+3][r2] = aw2.w;
        __syncthreads();
        if (ch + 1 < FB_NCH) {
            xp1 += FB_KC; xp2 += FB_KC; wp1 += FB_KC; wp2 += FB_KC;
            ax1 = *(const float4*)xp1; ax2 = *(const float4*)xp2;
            aw1 = *(const float4*)wp1; aw2 = *(const float4*)wp2;
        }
        #pragma unroll
        for (int k = 0; k < FB_KC; ++k) {
            float4 xa = *(const float4*)&sX[k][mq << 2];
            float4 wb = *(const float4*)&sW[k][nq << 2];
            float (*A)[4] = (k < FB_KC / 2) ? a1 : a2;
            A[0][0] = fmaf(xa.x, wb.x, A[0][0]); A[0][1] = fmaf(xa.x, wb.y, A[0][1]);
            A[0][2] = fmaf(xa.x, wb.z, A[0][2]); A[0][3] = fmaf(xa.x, wb.w, A[0][3]);
            A[1][0] = fmaf(xa.y, wb.x, A[1][0]); A[1][1] = fmaf(xa.y, wb.y, A[1][1]);
            A[1][2] = fmaf(xa.y, wb.z, A[1][2]); A[1][3] = fmaf(xa.y, wb.w, A[1][3]);
            A[2][0] = fmaf(xa.z, wb.x, A[2][0]); A[2][1] = fmaf(xa.z, wb.y, A[2][1]);
            A[2][2] = fmaf(xa.z, wb.z, A[2][2]); A[2][3] = fmaf(xa.z, wb.w, A[2][3]);
            A[3][0] = fmaf(xa.w, wb.x, A[3][0]); A[3][1] = fmaf(xa.w, wb.y, A[3][1]);
            A[3][2] = fmaf(xa.w, wb.z, A[3][2]); A[3][3] = fmaf(xa.w, wb.w, A[3][3]);
        }
    }
    #pragma unroll
    for (int i = 0; i < 4; ++i)
        #pragma unroll
        for (int j = 0; j < 4; ++j)
            sL[(mq << 2) + i][(nq << 2) + j] = a1[i][j] + a2[i][j];
    if (t < NE) hist[t] = 0;
    __syncthreads();
    if (t < 64) {
        const int m = t;
        float mx = sL[m][0]; int arg = 0;
        for (int e = 1; e < NE; ++e) { float v = sL[m][e]; if (v > mx) { mx = v; arg = e; } }
        float s = 0.f;
        for (int e = 0; e < NE; ++e) s += expf(sL[m][e] - mx);
        float inv = 1.f / s;
        out[m0 + m] = (float)arg; out[Ntok + m0 + m] = inv;
        smax[m] = mx; sinv[m] = inv;
        atomicAdd(&hist[arg], 1);
        float lse = mx + logf(s); float z = lse * lse;
        for (int off = 32; off > 0; off >>= 1) z += __shfl_down(z, off, 64);
        if (t == 0) ws_z[b] = z;
    }
    __syncthreads();
    {
        const int e = t & 63, mg = t >> 6;
        float pa = 0.f;
        for (int m = mg * 16; m < mg * 16 + 16; ++m) pa += expf(sL[m][e] - smax[m]) * sinv[m];
        spart[mg][e] = pa;
    }
    __syncthreads();
    if (t < NE) {
        ws_prob[b * NE + t] = spart[0][t] + spart[1][t] + spart[2][t] + spart[3][t];
        ws_cnt[b * NE + t]  = hist[t];
    }
}

extern "C" void kernel_launch(void* const* d_in, const int* in_sizes, int n_in,
                              void* d_out, int out_size, void* d_ws, size_t ws_size,
                              hipStream_t stream)
{
    const float* x = (const float*)d_in[0];
    const float* W = (const float*)d_in[1];
    float* out = (float*)d_out;

    const int Ntok   = in_sizes[0] / D_MODEL;        // 16384
    const int ntiles = Ntok / TB;                    // 256
    const int nstat  = Ntok / 64;                    // 256

    const size_t wh_elems   = (size_t)NE * D_MODEL;              // 131072 shorts
    const size_t part_elems = (size_t)ntiles * KS * TB * NE;     // 2.1M floats
    const size_t need = wh_elems * 2 * 2
                      + (part_elems + (size_t)nstat * NE + nstat) * 4
                      + (size_t)nstat * NE * 4 + 1024;

    if ((Ntok % TB) == 0 && ws_size >= need) {
        short* wsh    = (short*)d_ws;                // Wh [64][2048]
        short* wsl    = wsh + wh_elems;              // Wl
        float* ws_part = (float*)(wsl + wh_elems);
        float* ws_prob = ws_part + part_elems;
        float* ws_z    = ws_prob + (size_t)nstat * NE;
        int*   ws_cnt  = (int*)(ws_z + nstat);

        wcvt_kernel<<<NE, 256, 0, stream>>>(W, wsh, wsl);
        dim3 grid(ntiles, KS);
        router_mfma<<<grid, 256, 0, stream>>>(x, wsh, wsl, ws_part, ntiles);
        router_stats5<<<nstat, 1024, 0, stream>>>(ws_part, out, ws_prob, ws_z, ws_cnt, Ntok);
        router_final2<<<1, 256, 0, stream>>>(ws_prob, ws_z, ws_cnt, out, Ntok, nstat);
    } else {
        const int nb = Ntok / 64;
        float* ws_prob = (float*)d_ws;
        float* ws_z    = ws_prob + (size_t)nb * NE;
        int*   ws_cnt  = (int*)(ws_z + nb);
        router_main_fb<<<nb, 256, 0, stream>>>(x, W, out, ws_prob, ws_z, ws_cnt, Ntok);
        router_final2<<<1, 256, 0, stream>>>(ws_prob, ws_z, ws_cnt, out, Ntok, nb);
    }
}